// Round 5
// baseline (12014.697 us; speedup 1.0000x reference)
//
#include <hip/hip_runtime.h>

#define N_DIM 100000
#define M_DIM 200000
#define NNZ_A 2000000
#define NNZ_P 500000
#define NMSUM 300000
#define NM1   300001
#define CG_ITERS 20
#define TPB 256
#define NSLOT 512

#define GN_SLICES 1563          // ceil(N/64)
#define AR_SLICES 3125          // M/64
#define GN_CAP (1563L * 64 * 60)
#define AR_CAP (3125L * 64 * 32)
#define GN_BLKS ((N_DIM + TPB - 1) / TPB)   // 391
#define AR_BLKS ((M_DIM + TPB - 1) / TPB)   // 782

#define NB_CG 1024
#define NT_CG ((long)NB_CG * TPB)           // 262144 threads
#define REDSZ (20 * 5 * 64 + 21 * 64)       // per-iter {d1,d2,e1,e2,pq} slots + gamma slots

typedef unsigned long long ull;

__device__ __forceinline__ void blk_red_add(double v, double* dst) {
    __shared__ double sb[TPB];
    int tid = threadIdx.x;
    __syncthreads();
    sb[tid] = v;
    __syncthreads();
    for (int sh = TPB / 2; sh > 0; sh >>= 1) {
        if (tid < sh) sb[tid] += sb[tid + sh];
        __syncthreads();
    }
    if (tid == 0) atomicAdd(dst, sb[0]);
}

__device__ __forceinline__ double blk_reduce(double v, double* sb) {
    int tid = threadIdx.x;
    __syncthreads();
    sb[tid] = v;
    __syncthreads();
    for (int sh = TPB / 2; sh > 0; sh >>= 1) {
        if (tid < sh) sb[tid] += sb[tid + sh];
        __syncthreads();
    }
    double rv = sb[0];
    __syncthreads();
    return rv;
}

__device__ __forceinline__ double blk_sum64(const double* src, double* sb) {
    double v = (threadIdx.x < 64) ? src[threadIdx.x] : 0.0;
    return blk_reduce(v, sb);
}

// device-scope grid barrier: release-fence, arrive, generation spin, acquire-fence
__device__ __forceinline__ void gsync(unsigned* bar, unsigned* gen) {
    __syncthreads();
    if (threadIdx.x == 0) {
        __threadfence();   // release: L2 writeback to device scope
        unsigned g = __hip_atomic_load(gen, __ATOMIC_RELAXED, __HIP_MEMORY_SCOPE_AGENT);
        unsigned a = __hip_atomic_fetch_add(bar, 1u, __ATOMIC_RELAXED, __HIP_MEMORY_SCOPE_AGENT) + 1u;
        if (a == (unsigned)NB_CG) {
            __hip_atomic_store(bar, 0u, __ATOMIC_RELAXED, __HIP_MEMORY_SCOPE_AGENT);
            __hip_atomic_store(gen, g + 1u, __ATOMIC_RELEASE, __HIP_MEMORY_SCOPE_AGENT);
        } else {
            while (__hip_atomic_load(gen, __ATOMIC_RELAXED, __HIP_MEMORY_SCOPE_AGENT) == g) {
                __builtin_amdgcn_s_sleep(10);
            }
        }
        __threadfence();   // acquire: invalidate stale L2
    }
    __syncthreads();
}

__device__ __forceinline__ ull pk(int idx, float v) {
    return (ull)(unsigned)idx | ((ull)__float_as_uint(v) << 32);
}

// 8-class length classification (flavor 0: n-side lambda~25, flavor 1: m-side lambda~10)
__device__ __forceinline__ int classify(int len, int flavor) {
    if (flavor == 0) {
        if (len < 15) return 0; if (len < 19) return 1; if (len < 23) return 2;
        if (len < 26) return 3; if (len < 29) return 4; if (len < 33) return 5;
        if (len < 39) return 6; return 7;
    } else {
        if (len < 5)  return 0; if (len < 7)  return 1; if (len < 9)  return 2;
        if (len < 11) return 3; if (len < 13) return 4; if (len < 15) return 5;
        if (len < 19) return 6; return 7;
    }
}

// SELL-64 row dot, unroll 8: coalesced nt pair stream + L2 gathers
__device__ __forceinline__ double sell_dot(const ull* __restrict__ pair,
                                           const int* __restrict__ soff, int sr,
                                           const double* __restrict__ vin) {
    int s = sr >> 6;
    int o0 = soff[s], o1 = soff[s + 1];
    long base = (long)o0 + (sr & 63);
    int trips = (o1 - o0) >> 6;
    double acc = 0.0;
    int j = 0;
    for (; j + 8 <= trips; j += 8) {
        ull e0 = __builtin_nontemporal_load(pair + base + (long)(j + 0) * 64);
        ull e1 = __builtin_nontemporal_load(pair + base + (long)(j + 1) * 64);
        ull e2 = __builtin_nontemporal_load(pair + base + (long)(j + 2) * 64);
        ull e3 = __builtin_nontemporal_load(pair + base + (long)(j + 3) * 64);
        ull e4 = __builtin_nontemporal_load(pair + base + (long)(j + 4) * 64);
        ull e5 = __builtin_nontemporal_load(pair + base + (long)(j + 5) * 64);
        ull e6 = __builtin_nontemporal_load(pair + base + (long)(j + 6) * 64);
        ull e7 = __builtin_nontemporal_load(pair + base + (long)(j + 7) * 64);
        double g0 = vin[(unsigned)e0];
        double g1 = vin[(unsigned)e1];
        double g2 = vin[(unsigned)e2];
        double g3 = vin[(unsigned)e3];
        double g4 = vin[(unsigned)e4];
        double g5 = vin[(unsigned)e5];
        double g6 = vin[(unsigned)e6];
        double g7 = vin[(unsigned)e7];
        acc += (double)__uint_as_float((unsigned)(e0 >> 32)) * g0;
        acc += (double)__uint_as_float((unsigned)(e1 >> 32)) * g1;
        acc += (double)__uint_as_float((unsigned)(e2 >> 32)) * g2;
        acc += (double)__uint_as_float((unsigned)(e3 >> 32)) * g3;
        acc += (double)__uint_as_float((unsigned)(e4 >> 32)) * g4;
        acc += (double)__uint_as_float((unsigned)(e5 >> 32)) * g5;
        acc += (double)__uint_as_float((unsigned)(e6 >> 32)) * g6;
        acc += (double)__uint_as_float((unsigned)(e7 >> 32)) * g7;
    }
    for (; j < trips; ++j) {
        ull e = __builtin_nontemporal_load(pair + base + (long)j * 64);
        acc += (double)__uint_as_float((unsigned)(e >> 32)) * vin[(unsigned)e];
    }
    return acc;
}

__device__ __forceinline__ double sell_dot_dval(const ull* __restrict__ pair,
                                                const float* __restrict__ dval,
                                                const int* __restrict__ soff, int sr,
                                                const double* __restrict__ vin) {
    int s = sr >> 6;
    int o0 = soff[s], o1 = soff[s + 1];
    long base = (long)o0 + (sr & 63);
    int trips = (o1 - o0) >> 6;
    double acc = 0.0;
    for (int j = 0; j < trips; ++j) {
        long off = base + (long)j * 64;
        ull e = pair[off];
        acc += (double)dval[off] * vin[(unsigned)e];
    }
    return acc;
}

// ---------------- setup ----------------
__global__ __launch_bounds__(TPB) void k_init(double* sc, const float* y, const float* s,
                                              const float* x, double* mask_d, double* xpim,
                                              double* xcg,
                                              int* nP, int* cntGn, int* cntAr,
                                              int* curGn, int* curAr,
                                              double* red, unsigned* barg) {
    long i = (long)blockIdx.x * TPB + threadIdx.x;
    if (i < NSLOT) sc[i] = 0.0;
    if (i < REDSZ) red[i] = 0.0;
    if (i < 2) barg[i] = 0u;
    if (i < M_DIM) {
        double v = (double)y[i] - (double)s[i];
        mask_d[i] = v > 0.0 ? 1.0 : 0.0;
        xpim[N_DIM + i] = v > 0.0 ? v : 0.0;   // pi_m
        cntAr[i] = 0;
        curAr[i] = 0;
    }
    if (i < N_DIM) {
        xpim[i] = (double)x[i];
        nP[i] = 0; cntGn[i] = 0; curGn[i] = 0;
    }
    if (i < NM1) xcg[i] = 0.0;
}

__global__ __launch_bounds__(TPB) void k_hist(const int* Ar, const int* Ac, const int* Pr,
                                              int* nP, int* cntGn, int* cntAr) {
    long k = (long)blockIdx.x * TPB + threadIdx.x;
    if (k < NNZ_A) {
        atomicAdd(&cntGn[Ac[k]], 1);
        atomicAdd(&cntAr[Ar[k]], 1);
    }
    if (k < NNZ_P) atomicAdd(&nP[Pr[k]], 1);
}

__global__ __launch_bounds__(TPB) void k_comb(const int* nP, int* cntGn) {
    int i = blockIdx.x * TPB + threadIdx.x;
    if (i < N_DIM) cntGn[i] += nP[i];
}

// per-block class histogram + class id
__global__ __launch_bounds__(TPB) void k_cls(const int* cnt, int len, int flavor,
                                             int* cls, int* blkhist) {
    __shared__ int h[8];
    if (threadIdx.x < 8) h[threadIdx.x] = 0;
    __syncthreads();
    int i = blockIdx.x * TPB + threadIdx.x;
    if (i < len) {
        int c = classify(cnt[i], flavor);
        cls[i] = c;
        atomicAdd(&h[c], 1);
    }
    __syncthreads();
    if (threadIdx.x < 8) blkhist[blockIdx.x * 8 + threadIdx.x] = h[threadIdx.x];
}

// single-block: per-(block,class) exclusive offsets with global class bases
__global__ __launch_bounds__(64) void k_clsoff(int* blkhist, int nblk, int* off) {
    __shared__ int tot[8], cb[8];
    int t = threadIdx.x;
    if (t < 8) {
        int run = 0;
        for (int bkk = 0; bkk < nblk; ++bkk) {
            int v = blkhist[bkk * 8 + t];
            off[bkk * 8 + t] = run;
            run += v;
        }
        tot[t] = run;
    }
    __syncthreads();
    if (t == 0) {
        int base = 0;
        for (int c = 0; c < 8; ++c) { cb[c] = base; base += tot[c]; }
    }
    __syncthreads();
    if (t < 8) {
        for (int bkk = 0; bkk < nblk; ++bkk) off[bkk * 8 + t] += cb[t];
    }
}

__global__ __launch_bounds__(TPB) void k_rank(const int* cls, int len, const int* off,
                                              int* rank, int* perm) {
    __shared__ int cur[8];
    if (threadIdx.x < 8) cur[threadIdx.x] = off[blockIdx.x * 8 + threadIdx.x];
    __syncthreads();
    int i = blockIdx.x * TPB + threadIdx.x;
    if (i < len) {
        int c = cls[i];
        int rk = atomicAdd(&cur[c], 1);
        rank[i] = rk;
        perm[rk] = i;
    }
}

__global__ __launch_bounds__(TPB) void k_smax(const int* cnt, const int* perm,
                                              int nrows, int nslices, int* out64) {
    int s = blockIdx.x * TPB + threadIdx.x;
    if (s < nslices) {
        int lo = s * 64;
        int hi = lo + 64; if (hi > nrows) hi = nrows;
        int m = 0;
        for (int r0 = lo; r0 < hi; ++r0) m = max(m, cnt[perm[r0]]);
        out64[s] = m * 64;
    }
}

__global__ __launch_bounds__(TPB) void k_scan1(const int* cnt, int len, int* exc, int* blksum) {
    __shared__ int sb[TPB];
    int i = blockIdx.x * TPB + threadIdx.x;
    int v = (i < len) ? cnt[i] : 0;
    sb[threadIdx.x] = v;
    __syncthreads();
    for (int sh = 1; sh < TPB; sh <<= 1) {
        int t = (threadIdx.x >= sh) ? sb[threadIdx.x - sh] : 0;
        __syncthreads();
        sb[threadIdx.x] += t;
        __syncthreads();
    }
    if (i < len) exc[i] = sb[threadIdx.x] - v;
    if (threadIdx.x == TPB - 1) blksum[blockIdx.x] = sb[TPB - 1];
}

__global__ __launch_bounds__(1024) void k_scan2(int* blksum, int nb, int* total_out) {
    __shared__ int sb[1024];
    int t = threadIdx.x;
    int v = (t < nb) ? blksum[t] : 0;
    sb[t] = v;
    __syncthreads();
    for (int sh = 1; sh < 1024; sh <<= 1) {
        int x = (t >= sh) ? sb[t - sh] : 0;
        __syncthreads();
        sb[t] += x;
        __syncthreads();
    }
    if (t < nb) blksum[t] = sb[t] - v;
    if (t == nb - 1) *total_out = sb[t];
}

__global__ __launch_bounds__(TPB) void k_scan3(int* exc, const int* blksum, int len) {
    int i = blockIdx.x * TPB + threadIdx.x;
    if (i < len) exc[i] += blksum[blockIdx.x];
}

__global__ __launch_bounds__(TPB) void k_zero(ull* pairGn, float* dvalGn, const int* soffGn,
                                              ull* pairAr, float* dvalAr, const int* soffAr) {
    long k = (long)blockIdx.x * TPB + threadIdx.x;
    long tG = soffGn[GN_SLICES];
    long tA = soffAr[AR_SLICES];
    if (k < tG) { pairGn[k] = 0ull; dvalGn[k] = 0.0f; }
    if (k < tA) { pairAr[k] = 0ull; dvalAr[k] = 0.0f; }
}

// fill order: P entries FIRST per G_n row (prefix), then A^T entries
__global__ __launch_bounds__(TPB) void k_fillGnP(const int* Pr, const int* Pc, const float* Pv,
                                                 const float* dPv, const int* soffGn, int* curGn,
                                                 const int* rankGn, ull* pairGn, float* dvalGn) {
    long k = (long)blockIdx.x * TPB + threadIdx.x;
    if (k < NNZ_P) {
        int r0 = Pr[k];
        int j = atomicAdd(&curGn[r0], 1);
        int rk = rankGn[r0];
        long pos = (long)soffGn[rk >> 6] + (long)j * 64 + (rk & 63);
        pairGn[pos] = pk(Pc[k], Pv[k]);
        dvalGn[pos] = dPv[k];
    }
}
__global__ __launch_bounds__(TPB) void k_fillGnA(const int* Ar, const int* Ac, const float* Av,
                                                 const float* dAv, const int* soffGn, int* curGn,
                                                 const int* rankGn, ull* pairGn, float* dvalGn) {
    long k = (long)blockIdx.x * TPB + threadIdx.x;
    if (k < NNZ_A) {
        int r0 = Ac[k];
        int j = atomicAdd(&curGn[r0], 1);
        int rk = rankGn[r0];
        long pos = (long)soffGn[rk >> 6] + (long)j * 64 + (rk & 63);
        pairGn[pos] = pk(N_DIM + Ar[k], Av[k]);
        dvalGn[pos] = dAv[k];
    }
}
__global__ __launch_bounds__(TPB) void k_fillAr2(const int* Ar, const int* Ac, const float* Av,
                                                 const float* dAv, const int* soffAr, int* curAr,
                                                 const int* rankAr, ull* pairAr, float* dvalAr) {
    long k = (long)blockIdx.x * TPB + threadIdx.x;
    if (k < NNZ_A) {
        int r0 = Ar[k];
        int j = atomicAdd(&curAr[r0], 1);
        int rk = rankAr[r0];
        long pos = (long)soffAr[rk >> 6] + (long)j * 64 + (rk & 63);
        pairAr[pos] = pk(Ac[k], Av[k]);
        dvalAr[pos] = dAv[k];
    }
}

// fused: Px, dpx, c3, dd_n  (P entries are the nP-prefix of each G_n row)
__global__ __launch_bounds__(TPB) void k_setup_n(const ull* __restrict__ pairGn,
                                                 const float* __restrict__ dvalGn,
                                                 const int* __restrict__ soffGn,
                                                 const int* __restrict__ permGn,
                                                 const int* __restrict__ nP,
                                                 const double* __restrict__ xpim,
                                                 const float* __restrict__ q,
                                                 const float* __restrict__ dq,
                                                 double* Px, double* dpx, double* c3, double* dd) {
    int sr = blockIdx.x * TPB + threadIdx.x;
    if (sr >= N_DIM) return;
    int i = permGn[sr];
    int s = sr >> 6;
    int o0 = soffGn[s], o1 = soffGn[s + 1];
    long base = (long)o0 + (sr & 63);
    int trips = (o1 - o0) >> 6;
    int np = nP[i];
    double px = 0.0, dpxv = 0.0, sa = 0.0;
    for (int j = 0; j < trips; ++j) {
        long off = base + (long)j * 64;
        ull e = pairGn[off];
        float dv = dvalGn[off];
        double g = xpim[(unsigned)e];
        if (j < np) {
            px += (double)__uint_as_float((unsigned)(e >> 32)) * g;
            dpxv += (double)dv * g;
        } else {
            sa += (double)dv * g;
        }
    }
    Px[i] = px;
    dpx[i] = dpxv;
    c3[i] = (double)q[i] + 2.0 * px;
    dd[i] = dpxv + sa + (double)dq[i];
}

__global__ __launch_bounds__(TPB) void k_setup_m(const ull* __restrict__ pairAr,
                                                 const float* __restrict__ dvalAr,
                                                 const int* __restrict__ soffAr,
                                                 const int* __restrict__ permAr,
                                                 const double* __restrict__ xpim,
                                                 const float* __restrict__ db, double* dd) {
    int sr = blockIdx.x * TPB + threadIdx.x;
    if (sr >= M_DIM) return;
    int j = permAr[sr];
    double s = sell_dot_dval(pairAr, dvalAr, soffAr, sr, xpim);
    dd[N_DIM + j] = -s + (double)db[j];
}

__global__ __launch_bounds__(TPB) void k_dot_fd(const float* a, const double* b, long len, double* dst) {
    long i = (long)blockIdx.x * TPB + threadIdx.x;
    double loc = 0.0;
    if (i < len) loc = (double)a[i] * b[i];
    blk_red_add(loc, dst);
}
__global__ __launch_bounds__(TPB) void k_dot_ff(const float* a, const float* b, long len, double* dst) {
    long i = (long)blockIdx.x * TPB + threadIdx.x;
    double loc = 0.0;
    if (i < len) loc = (double)a[i] * (double)b[i];
    blk_red_add(loc, dst);
}
__global__ __launch_bounds__(64) void k_dd_t(double* sc, double* dd) {
    if (threadIdx.x == 0) dd[NMSUM] = -sc[1] - sc[2] - sc[3];
}
// dd = -dd ; WC = [W_n ; -W_m]  (W = new dd)
__global__ __launch_bounds__(TPB) void k_negWC(double* dd, double* WC) {
    int i = blockIdx.x * TPB + threadIdx.x;
    if (i < NM1) {
        double nv = -dd[i];
        dd[i] = nv;
        if (i < N_DIM) WC[i] = nv;
        else if (i < NMSUM) WC[i] = -nv;
    }
}
__global__ __launch_bounds__(TPB) void k_rn(const ull* __restrict__ pairGn,
                                            const int* __restrict__ soffGn,
                                            const int* __restrict__ permGn,
                                            const double* __restrict__ WC,
                                            const double* __restrict__ c3,
                                            const double* __restrict__ dd, double* r) {
    int sr = blockIdx.x * TPB + threadIdx.x;
    if (sr >= N_DIM) return;
    int i = permGn[sr];
    double s = sell_dot(pairGn, soffGn, sr, WC);
    r[i] = s - c3[i] * dd[NMSUM];
}
__global__ __launch_bounds__(TPB) void k_rm(const ull* __restrict__ pairAr,
                                            const int* __restrict__ soffAr,
                                            const int* __restrict__ permAr,
                                            const double* __restrict__ WC,
                                            const double* __restrict__ mask_d,
                                            const float* __restrict__ b,
                                            const double* __restrict__ dd, double* r) {
    int sr = blockIdx.x * TPB + threadIdx.x;
    if (sr >= M_DIM) return;
    int j = permAr[sr];
    double s = sell_dot(pairAr, soffAr, sr, WC);
    double wt = dd[NMSUM];
    double tmv = s - (double)b[j] * wt;
    double wm = dd[N_DIM + j];
    r[N_DIM + j] = mask_d[j] * (tmv - wm) + wm;
}
__global__ __launch_bounds__(64) void k_ft_t(const double* e1, const double* e2, const double* xtpx,
                                             const double* W, double* U) {
    if (threadIdx.x == 0) U[NMSUM] = (*e1) + (*e2) + (*xtpx) * W[NMSUM];
}

// ---------------- persistent CG kernel: 20 iterations, 80 grid barriers ----------------
__global__ __launch_bounds__(TPB, 4) void k_cg(
    const ull* __restrict__ pairGn, const int* __restrict__ soffGn,
    const ull* __restrict__ pairAr, const int* __restrict__ soffAr,
    const int* __restrict__ permGn, const int* __restrict__ permAr,
    const float* __restrict__ q, const float* __restrict__ b,
    const double* __restrict__ mask_d, const double* __restrict__ c3,
    double* __restrict__ r, double* __restrict__ p,
    double* __restrict__ pum, double* __restrict__ Fpc,
    double* __restrict__ Ap, double* __restrict__ xcg,
    double* sc, double* red, unsigned* barg) {
    __shared__ double sb[TPB];
    const int tid = threadIdx.x;
    const long gtid = (long)blockIdx.x * TPB + tid;
    const int slot = blockIdx.x & 63;
    double* gs = red + 20 * 5 * 64;       // gamma slots [21][64]
    const double xtpx = sc[0];

    // phase 0: p = r, pum, d1/d2 partials, ||r||^2 partials
    double l1 = 0.0, l2 = 0.0, l3 = 0.0;
    for (long sr = gtid; sr < NM1; sr += NT_CG) {
        double v = r[sr]; p[sr] = v; l3 += v * v;
        if (sr < N_DIM) { l1 += c3[sr] * v; pum[sr] = v; }
        else if (sr < NMSUM) {
            long j = sr - N_DIM;
            double u = mask_d[j] * v; pum[sr] = u; l2 += (double)b[j] * u;
        }
    }
    { double t = blk_reduce(l1, sb); if (tid == 0) atomicAdd(&red[0 * 64 + slot], t); }
    { double t = blk_reduce(l2, sb); if (tid == 0) atomicAdd(&red[1 * 64 + slot], t); }
    { double t = blk_reduce(l3, sb); if (tid == 0) atomicAdd(&gs[0 * 64 + slot], t); }
    gsync(barg, barg + 1);
    double gcur = blk_sum64(gs, sb);

    for (int it = 0; it < CG_ITERS; ++it) {
        double* rb = red + (long)it * 5 * 64;
        if (it > 0) {
            // phase A: beta, p update, pum, d1/d2 partials
            double gnext = blk_sum64(gs + (long)it * 64, sb);
            double beta = gnext / gcur;
            gcur = gnext;
            l1 = 0.0; l2 = 0.0;
            for (long sr = gtid; sr < NM1; sr += NT_CG) {
                double pn = r[sr] + beta * p[sr]; p[sr] = pn;
                if (sr < N_DIM) { l1 += c3[sr] * pn; pum[sr] = pn; }
                else if (sr < NMSUM) {
                    long j = sr - N_DIM;
                    double u = mask_d[j] * pn; pum[sr] = u; l2 += (double)b[j] * u;
                }
            }
            { double t = blk_reduce(l1, sb); if (tid == 0) atomicAdd(&rb[0 * 64 + slot], t); }
            { double t = blk_reduce(l2, sb); if (tid == 0) atomicAdd(&rb[1 * 64 + slot], t); }
            gsync(barg, barg + 1);
        }
        // phase B: Fmv (SELL dots over pum) + e1/e2 partials; tau thread -> sc[10]
        double ut = p[NMSUM];
        l1 = 0.0; l2 = 0.0;
        for (long sr = gtid; sr < NM1; sr += NT_CG) {
            if (sr < N_DIM) {
                int i = permGn[sr];
                double s = sell_dot(pairGn, soffGn, (int)sr, pum);   // P p + A^T um
                double r1 = s + (double)q[i] * ut;
                double v = (r1 - p[i]) + p[i];
                Fpc[i] = v;
                l1 += (double)q[i] * v;
            } else if (sr < NMSUM) {
                int j = permAr[sr - N_DIM];
                int gj = N_DIM + j;
                double s = sell_dot(pairAr, soffAr, (int)(sr - N_DIM), pum);  // A p_n
                double r2 = -s + (double)b[j] * ut;
                double v = (r2 - pum[gj]) + p[gj];
                Fpc[gj] = -v;
                l2 += (double)b[j] * v;
            } else {
                double d1 = 0.0, d2 = 0.0;
                for (int k2 = 0; k2 < 64; ++k2) { d1 += rb[0 * 64 + k2]; d2 += rb[1 * 64 + k2]; }
                double r3 = -d1 - d2 + xtpx * ut;
                sc[10] = (r3 - ut) + ut;                            // F_tau
            }
        }
        { double t = blk_reduce(l1, sb); if (tid == 0) atomicAdd(&rb[2 * 64 + slot], t); }
        { double t = blk_reduce(l2, sb); if (tid == 0) atomicAdd(&rb[3 * 64 + slot], t); }
        gsync(barg, barg + 1);
        // phase C: FTmv (SELL dots over Fpc) + pq partials
        double wt = sc[10];
        double l = 0.0;
        for (long sr = gtid; sr < NM1; sr += NT_CG) {
            if (sr < N_DIM) {
                int i = permGn[sr];
                double s = sell_dot(pairGn, soffGn, (int)sr, Fpc);  // P Fp_n - A^T Fp_m
                double v = s - c3[i] * wt;
                Ap[i] = v;
                l += p[i] * v;
            } else if (sr < NMSUM) {
                int j = permAr[sr - N_DIM];
                int gj = N_DIM + j;
                double s = sell_dot(pairAr, soffAr, (int)(sr - N_DIM), Fpc); // A Fp_n
                double tmv = s - (double)b[j] * wt;
                double wm = -Fpc[gj];
                double v = mask_d[j] * (tmv - wm) + wm;
                Ap[gj] = v;
                l += p[gj] * v;
            } else {
                double e1 = 0.0, e2 = 0.0;
                for (int k2 = 0; k2 < 64; ++k2) { e1 += rb[2 * 64 + k2]; e2 += rb[3 * 64 + k2]; }
                double tt = e1 + e2 + xtpx * wt;
                Ap[NMSUM] = tt;
                l += p[NMSUM] * tt;
            }
        }
        { double t = blk_reduce(l, sb); if (tid == 0) atomicAdd(&rb[4 * 64 + slot], t); }
        gsync(barg, barg + 1);
        // phase D: alpha, x/r update, ||r||^2 partials
        double pq = blk_sum64(rb + 4 * 64, sb);
        double alpha = gcur / pq;
        l = 0.0;
        for (long sr = gtid; sr < NM1; sr += NT_CG) {
            xcg[sr] += alpha * p[sr];
            double rn = r[sr] - alpha * Ap[sr];
            r[sr] = rn;
            l += rn * rn;
        }
        { double t = blk_reduce(l, sb); if (tid == 0) atomicAdd(&gs[(long)(it + 1) * 64 + slot], t); }
        gsync(barg, barg + 1);
    }
}

__global__ __launch_bounds__(TPB) void k_final(const double* xcg, const double* mask_d,
                                               const float* x, const float* y, const float* s,
                                               float* out) {
    int i = blockIdx.x * TPB + threadIdx.x;
    double dzt = xcg[NMSUM];
    if (i < N_DIM) {
        out[i] = (float)(xcg[i] - (double)x[i] * dzt);
    } else if (i < NMSUM) {
        int j = i - N_DIM;
        double dzm = xcg[N_DIM + j];
        double t = mask_d[j] * dzm;
        out[N_DIM + j] = (float)(t - (double)y[j] * dzt);
        out[N_DIM + M_DIM + j] = (float)(t - dzm - (double)s[j] * dzt);
    }
}

extern "C" void kernel_launch(void* const* d_in, const int* in_sizes, int n_in,
                              void* d_out, int out_size, void* d_ws, size_t ws_size,
                              hipStream_t stream) {
    const int*   Pr  = (const int*)d_in[0];
    const int*   Pc  = (const int*)d_in[1];
    const float* Pv  = (const float*)d_in[2];
    const int*   Ar  = (const int*)d_in[3];
    const int*   Ac  = (const int*)d_in[4];
    const float* Av  = (const float*)d_in[5];
    const float* q   = (const float*)d_in[6];
    const float* b   = (const float*)d_in[7];
    const float* x   = (const float*)d_in[8];
    const float* yv  = (const float*)d_in[9];
    const float* sv  = (const float*)d_in[10];
    const float* dPv = (const float*)d_in[11];
    const float* dAv = (const float*)d_in[12];
    const float* dq  = (const float*)d_in[13];
    const float* db  = (const float*)d_in[14];
    float* out = (float*)d_out;

    char* wp = (char*)d_ws;
    auto alloc = [&](size_t bytes) { char* r0 = wp; wp += (bytes + 255) & ~255ull; return r0; };

    double* sc     = (double*)alloc(NSLOT * 8);
    double* mask_d = (double*)alloc((size_t)M_DIM * 8);
    double* xpim   = (double*)alloc((size_t)NMSUM * 8);   // [x ; pi_m]
    double* Px     = (double*)alloc((size_t)N_DIM * 8);
    double* dpx    = (double*)alloc((size_t)N_DIM * 8);
    double* c3     = (double*)alloc((size_t)N_DIM * 8);
    double* dd     = (double*)alloc((size_t)NM1 * 8);
    double* r      = (double*)alloc((size_t)NM1 * 8);
    double* p      = (double*)alloc((size_t)NM1 * 8);
    double* xcg    = (double*)alloc((size_t)NM1 * 8);
    double* Ap     = (double*)alloc((size_t)NM1 * 8);
    double* pum    = (double*)alloc((size_t)NMSUM * 8);   // [p_n ; um]
    double* Fpc    = (double*)alloc((size_t)NMSUM * 8);   // [Fp_n ; -Fp_m]
    double* WC     = (double*)alloc((size_t)NMSUM * 8);   // [W_n ; -W_m]
    double* red    = (double*)alloc((size_t)REDSZ * 8);
    unsigned* barg = (unsigned*)alloc(256);
    ull*   pairGn = (ull*)alloc((size_t)GN_CAP * 8);
    ull*   pairAr = (ull*)alloc((size_t)AR_CAP * 8);
    float* dvalGn = (float*)alloc((size_t)GN_CAP * 4);
    float* dvalAr = (float*)alloc((size_t)AR_CAP * 4);
    int*   nP     = (int*)alloc((size_t)N_DIM * 4);
    int*   cntGn  = (int*)alloc((size_t)N_DIM * 4);
    int*   cntAr  = (int*)alloc((size_t)M_DIM * 4);
    int*   curGn  = (int*)alloc((size_t)N_DIM * 4);
    int*   curAr  = (int*)alloc((size_t)M_DIM * 4);
    int*   clsGn  = (int*)alloc((size_t)N_DIM * 4);
    int*   clsAr  = (int*)alloc((size_t)M_DIM * 4);
    int*   rankGn = (int*)alloc((size_t)N_DIM * 4);
    int*   rankAr = (int*)alloc((size_t)M_DIM * 4);
    int*   permGn = (int*)alloc((size_t)N_DIM * 4);
    int*   permAr = (int*)alloc((size_t)M_DIM * 4);
    int*   blkhGn = (int*)alloc((size_t)GN_BLKS * 8 * 4);
    int*   blkhAr = (int*)alloc((size_t)AR_BLKS * 8 * 4);
    int*   offGn  = (int*)alloc((size_t)GN_BLKS * 8 * 4);
    int*   offAr  = (int*)alloc((size_t)AR_BLKS * 8 * 4);
    int*   smaxGn = (int*)alloc((size_t)GN_SLICES * 4);
    int*   smaxAr = (int*)alloc((size_t)AR_SLICES * 4);
    int*   soffGn = (int*)alloc((size_t)(GN_SLICES + 1) * 4);
    int*   soffAr = (int*)alloc((size_t)(AR_SLICES + 1) * 4);
    int*   blks   = (int*)alloc(1024 * 4);

    double* xtpx = sc + 0;

    auto g = [](long n) { return dim3((unsigned)((n + TPB - 1) / TPB)); };

    // ---- SELL-class build ----
    hipLaunchKernelGGL(k_init, g(NM1), dim3(TPB), 0, stream, sc, yv, sv, x, mask_d, xpim, xcg,
                       nP, cntGn, cntAr, curGn, curAr, red, barg);
    hipLaunchKernelGGL(k_hist, g(NNZ_A), dim3(TPB), 0, stream, Ar, Ac, Pr, nP, cntGn, cntAr);
    hipLaunchKernelGGL(k_comb, g(N_DIM), dim3(TPB), 0, stream, nP, cntGn);

    hipLaunchKernelGGL(k_cls, g(N_DIM), dim3(TPB), 0, stream, cntGn, N_DIM, 0, clsGn, blkhGn);
    hipLaunchKernelGGL(k_cls, g(M_DIM), dim3(TPB), 0, stream, cntAr, M_DIM, 1, clsAr, blkhAr);
    hipLaunchKernelGGL(k_clsoff, dim3(1), dim3(64), 0, stream, blkhGn, GN_BLKS, offGn);
    hipLaunchKernelGGL(k_clsoff, dim3(1), dim3(64), 0, stream, blkhAr, AR_BLKS, offAr);
    hipLaunchKernelGGL(k_rank, g(N_DIM), dim3(TPB), 0, stream, clsGn, N_DIM, offGn, rankGn, permGn);
    hipLaunchKernelGGL(k_rank, g(M_DIM), dim3(TPB), 0, stream, clsAr, M_DIM, offAr, rankAr, permAr);

    hipLaunchKernelGGL(k_smax, g(GN_SLICES), dim3(TPB), 0, stream, cntGn, permGn, N_DIM, GN_SLICES, smaxGn);
    hipLaunchKernelGGL(k_smax, g(AR_SLICES), dim3(TPB), 0, stream, cntAr, permAr, M_DIM, AR_SLICES, smaxAr);

    auto scan = [&](int* cnt, int len, int* soff) {
        int nb = (len + TPB - 1) / TPB;
        hipLaunchKernelGGL(k_scan1, dim3((unsigned)nb), dim3(TPB), 0, stream, cnt, len, soff, blks);
        hipLaunchKernelGGL(k_scan2, dim3(1), dim3(1024), 0, stream, blks, nb, soff + len);
        hipLaunchKernelGGL(k_scan3, dim3((unsigned)nb), dim3(TPB), 0, stream, soff, blks, len);
    };
    scan(smaxGn, GN_SLICES, soffGn);
    scan(smaxAr, AR_SLICES, soffAr);

    hipLaunchKernelGGL(k_zero, g(AR_CAP > GN_CAP ? AR_CAP : GN_CAP), dim3(TPB), 0, stream,
                       pairGn, dvalGn, soffGn, pairAr, dvalAr, soffAr);
    hipLaunchKernelGGL(k_fillGnP, g(NNZ_P), dim3(TPB), 0, stream, Pr, Pc, Pv, dPv, soffGn, curGn, rankGn, pairGn, dvalGn);
    hipLaunchKernelGGL(k_fillGnA, g(NNZ_A), dim3(TPB), 0, stream, Ar, Ac, Av, dAv, soffGn, curGn, rankGn, pairGn, dvalGn);
    hipLaunchKernelGGL(k_fillAr2, g(NNZ_A), dim3(TPB), 0, stream, Ar, Ac, Av, dAv, soffAr, curAr, rankAr, pairAr, dvalAr);

    // ---- setup math ----
    hipLaunchKernelGGL(k_setup_n, g(N_DIM), dim3(TPB), 0, stream, pairGn, dvalGn, soffGn, permGn, nP,
                       xpim, q, dq, Px, dpx, c3, dd);
    hipLaunchKernelGGL(k_setup_m, g(M_DIM), dim3(TPB), 0, stream, pairAr, dvalAr, soffAr, permAr, xpim, db, dd);
    hipLaunchKernelGGL(k_dot_fd, g(N_DIM), dim3(TPB), 0, stream, x, Px, (long)N_DIM, xtpx);
    hipLaunchKernelGGL(k_dot_ff, g(N_DIM), dim3(TPB), 0, stream, dq, x, (long)N_DIM, sc + 1);
    hipLaunchKernelGGL(k_dot_fd, g(M_DIM), dim3(TPB), 0, stream, db, xpim + N_DIM, (long)M_DIM, sc + 2);
    hipLaunchKernelGGL(k_dot_fd, g(N_DIM), dim3(TPB), 0, stream, x, dpx, (long)N_DIM, sc + 3);
    hipLaunchKernelGGL(k_dd_t, dim3(1), dim3(64), 0, stream, sc, dd);
    hipLaunchKernelGGL(k_negWC, g(NM1), dim3(TPB), 0, stream, dd, WC);
    hipLaunchKernelGGL(k_rn, g(N_DIM), dim3(TPB), 0, stream, pairGn, soffGn, permGn, WC, c3, dd, r);
    hipLaunchKernelGGL(k_rm, g(M_DIM), dim3(TPB), 0, stream, pairAr, soffAr, permAr, WC, mask_d, b, dd, r);
    hipLaunchKernelGGL(k_dot_fd, g(N_DIM), dim3(TPB), 0, stream, q, dd, (long)N_DIM, sc + 8);
    hipLaunchKernelGGL(k_dot_fd, g(M_DIM), dim3(TPB), 0, stream, b, dd + N_DIM, (long)M_DIM, sc + 9);
    hipLaunchKernelGGL(k_ft_t, dim3(1), dim3(64), 0, stream, sc + 8, sc + 9, xtpx, dd, r);

    // ---- persistent CG loop: one dispatch, 80 grid barriers ----
    hipLaunchKernelGGL(k_cg, dim3(NB_CG), dim3(TPB), 0, stream,
                       pairGn, soffGn, pairAr, soffAr, permGn, permAr,
                       q, b, mask_d, c3, r, p, pum, Fpc, Ap, xcg, sc, red, barg);

    hipLaunchKernelGGL(k_final, g(NMSUM), dim3(TPB), 0, stream, xcg, mask_d, x, yv, sv, out);
}

// Round 6
// 5863.265 us; speedup vs baseline: 2.0491x; 2.0491x over previous
//
#include <hip/hip_runtime.h>

#define N_DIM 100000
#define M_DIM 200000
#define NNZ_A 2000000
#define NNZ_P 500000
#define NMSUM 300000
#define NM1   300001
#define CG_ITERS 20
#define TPB 256
#define NSLOT 512

// slots: sc[0]=xTPx, sc[1..3]=dd_t dots, sc[8..9]=rhs-FTmv dots,
// per-iter base 16+8*it: {d1,d2,e1,e2,pq}, gam[] at sc+432 (0..50)

__device__ __forceinline__ void blk_red_add(double v, double* dst) {
    __shared__ double sb[TPB];
    int tid = threadIdx.x;
    __syncthreads();
    sb[tid] = v;
    __syncthreads();
    for (int sh = TPB / 2; sh > 0; sh >>= 1) {
        if (tid < sh) sb[tid] += sb[tid + sh];
        __syncthreads();
    }
    if (tid == 0) atomicAdd(dst, sb[0]);
}

// 4-way unrolled CSR row gather (thread-per-row, setup kernels)
__device__ __forceinline__ double row_dot(const int2* __restrict__ pair, int beg, int end,
                                          const double* __restrict__ vin) {
    double s = 0.0;
    int k = beg;
    for (; k + 4 <= end; k += 4) {
        int2 a0 = pair[k];
        int2 a1 = pair[k + 1];
        int2 a2 = pair[k + 2];
        int2 a3 = pair[k + 3];
        double g0 = vin[a0.x];
        double g1 = vin[a1.x];
        double g2 = vin[a2.x];
        double g3 = vin[a3.x];
        s += (double)__int_as_float(a0.y) * g0;
        s += (double)__int_as_float(a1.y) * g1;
        s += (double)__int_as_float(a2.y) * g2;
        s += (double)__int_as_float(a3.y) * g3;
    }
    for (; k < end; ++k) {
        int2 a = pair[k];
        s += (double)__int_as_float(a.y) * vin[a.x];
    }
    return s;
}

__device__ __forceinline__ double row_dot_d(const int2* __restrict__ pair,
                                            const float* __restrict__ dval, int beg, int end,
                                            const double* __restrict__ vin) {
    double s = 0.0;
    int k = beg;
    for (; k + 4 <= end; k += 4) {
        int c0 = pair[k].x, c1 = pair[k + 1].x, c2 = pair[k + 2].x, c3v = pair[k + 3].x;
        float d0 = dval[k], d1 = dval[k + 1], d2 = dval[k + 2], d3 = dval[k + 3];
        double g0 = vin[c0], g1 = vin[c1], g2 = vin[c2], g3 = vin[c3v];
        s += (double)d0 * g0;
        s += (double)d1 * g1;
        s += (double)d2 * g2;
        s += (double)d3 * g3;
    }
    for (; k < end; ++k)
        s += (double)dval[k] * vin[pair[k].x];
    return s;
}

// quad-per-row CSR gather: lane l of a 4-lane quad handles nnz l, l+4, ... (2-way unrolled)
// returns full row sum in all 4 lanes (two xor-shuffles)
__device__ __forceinline__ double row_dot_quad(const int2* __restrict__ pair, int beg, int end,
                                               const double* __restrict__ vin, int lane) {
    double s = 0.0;
    int k = beg + lane;
    for (; k + 4 < end; k += 8) {
        int2 a0 = pair[k];
        int2 a1 = pair[k + 4];
        double g0 = vin[a0.x];
        double g1 = vin[a1.x];
        s += (double)__int_as_float(a0.y) * g0;
        s += (double)__int_as_float(a1.y) * g1;
    }
    if (k < end) {
        int2 a = pair[k];
        s += (double)__int_as_float(a.y) * vin[a.x];
    }
    s += __shfl_xor(s, 1);
    s += __shfl_xor(s, 2);
    return s;
}

// ---------------- setup: init + histogram + scan + fill ----------------
__global__ __launch_bounds__(TPB) void k_init(double* sc, const float* y, const float* s,
                                              const float* x, double* mask_d, double* pim_d,
                                              double* xd, double* xcg,
                                              int* cntR, int* cntC, int* cntP) {
    long i = (long)blockIdx.x * TPB + threadIdx.x;
    if (i < NSLOT) sc[i] = 0.0;
    if (i < M_DIM) {
        double v = (double)y[i] - (double)s[i];
        mask_d[i] = v > 0.0 ? 1.0 : 0.0;
        pim_d[i]  = v > 0.0 ? v : 0.0;
        cntR[i] = 0;
    }
    if (i < N_DIM) { xd[i] = (double)x[i]; cntC[i] = 0; cntP[i] = 0; }
    if (i < NM1) xcg[i] = 0.0;
}

__global__ __launch_bounds__(TPB) void k_hist(const int* Ar, const int* Ac, const int* Pr,
                                              int* cntR, int* cntC, int* cntP) {
    long k = (long)blockIdx.x * TPB + threadIdx.x;
    if (k < NNZ_A) {
        atomicAdd(&cntR[Ar[k]], 1);
        atomicAdd(&cntC[Ac[k]], 1);
    }
    if (k < NNZ_P) atomicAdd(&cntP[Pr[k]], 1);
}

__global__ __launch_bounds__(TPB) void k_scan1(const int* cnt, int len, int* exc, int* blksum) {
    __shared__ int sb[TPB];
    int i = blockIdx.x * TPB + threadIdx.x;
    int v = (i < len) ? cnt[i] : 0;
    sb[threadIdx.x] = v;
    __syncthreads();
    for (int sh = 1; sh < TPB; sh <<= 1) {
        int t = (threadIdx.x >= sh) ? sb[threadIdx.x - sh] : 0;
        __syncthreads();
        sb[threadIdx.x] += t;
        __syncthreads();
    }
    if (i < len) exc[i] = sb[threadIdx.x] - v;
    if (threadIdx.x == TPB - 1) blksum[blockIdx.x] = sb[TPB - 1];
}

__global__ __launch_bounds__(1024) void k_scan2(int* blksum, int nb, int* total_out) {
    __shared__ int sb[1024];
    int t = threadIdx.x;
    int v = (t < nb) ? blksum[t] : 0;
    sb[t] = v;
    __syncthreads();
    for (int sh = 1; sh < 1024; sh <<= 1) {
        int x = (t >= sh) ? sb[t - sh] : 0;
        __syncthreads();
        sb[t] += x;
        __syncthreads();
    }
    if (t < nb) blksum[t] = sb[t] - v;          // exclusive block offsets
    if (t == nb - 1) *total_out = sb[t];        // rptr[len] = total
}

__global__ __launch_bounds__(TPB) void k_scan3(int* exc, const int* blksum, int len, int* cur) {
    int i = blockIdx.x * TPB + threadIdx.x;
    if (i < len) {
        int v = exc[i] + blksum[blockIdx.x];
        exc[i] = v;
        cur[i] = v;
    }
}

// Split fills: each kernel's scatter working set fits aggregate L2
__global__ __launch_bounds__(TPB) void k_fillAr(const int* Ar, const int* Ac, const float* Av,
                                                const float* dAv, int* curR,
                                                int2* pAr, float* dvalAr) {
    long k = (long)blockIdx.x * TPB + threadIdx.x;
    if (k < NNZ_A) {
        int pos = atomicAdd(&curR[Ar[k]], 1);
        pAr[pos] = make_int2(Ac[k], __float_as_int(Av[k]));
        dvalAr[pos] = dAv[k];
    }
}
__global__ __launch_bounds__(TPB) void k_fillAc(const int* Ar, const int* Ac, const float* Av,
                                                const float* dAv, int* curC,
                                                int2* pAc, float* dvalAc) {
    long k = (long)blockIdx.x * TPB + threadIdx.x;
    if (k < NNZ_A) {
        int pos = atomicAdd(&curC[Ac[k]], 1);
        pAc[pos] = make_int2(Ar[k], __float_as_int(Av[k]));
        dvalAc[pos] = dAv[k];
    }
}
__global__ __launch_bounds__(TPB) void k_fillP(const int* Pr, const int* Pc, const float* Pv,
                                               const float* dPv, int* curP,
                                               int2* pP, float* dvalP) {
    long k = (long)blockIdx.x * TPB + threadIdx.x;
    if (k < NNZ_P) {
        int pos = atomicAdd(&curP[Pr[k]], 1);
        pP[pos] = make_int2(Pc[k], __float_as_int(Pv[k]));
        dvalP[pos] = dPv[k];
    }
}

// ---------------- generic CSR gather SpMV (setup) ----------------
__global__ __launch_bounds__(TPB) void k_csr(const int* rptr, const int2* pair,
                                             const double* vin, double* vout,
                                             double sgn, int accum, int nrows) {
    int i = blockIdx.x * TPB + threadIdx.x;
    if (i >= nrows) return;
    double s = row_dot(pair, rptr[i], rptr[i + 1], vin) * sgn;
    vout[i] = accum ? (vout[i] + s) : s;
}

__global__ __launch_bounds__(TPB) void k_csr_d(const int* rptr, const int2* pair,
                                               const float* dval, const double* vin,
                                               double* vout, double sgn, int accum, int nrows) {
    int i = blockIdx.x * TPB + threadIdx.x;
    if (i >= nrows) return;
    double s = row_dot_d(pair, dval, rptr[i], rptr[i + 1], vin) * sgn;
    vout[i] = accum ? (vout[i] + s) : s;
}

// ---------------- dots & small elementwise (unchanged math) ----------------
__global__ __launch_bounds__(TPB) void k_dot_fd(const float* a, const double* b, long len, double* dst) {
    long i = (long)blockIdx.x * TPB + threadIdx.x;
    double loc = 0.0;
    if (i < len) loc = (double)a[i] * b[i];
    blk_red_add(loc, dst);
}
__global__ __launch_bounds__(TPB) void k_dot_ff(const float* a, const float* b, long len, double* dst) {
    long i = (long)blockIdx.x * TPB + threadIdx.x;
    double loc = 0.0;
    if (i < len) loc = (double)a[i] * (double)b[i];
    blk_red_add(loc, dst);
}
__global__ __launch_bounds__(TPB) void k_c3e(const float* q, const double* Px, double* c3) {
    int i = blockIdx.x * TPB + threadIdx.x;
    if (i < N_DIM) c3[i] = (double)q[i] + 2.0 * Px[i];
}
__global__ __launch_bounds__(TPB) void k_dd_n(const double* dpx, const float* dq, double* dd) {
    int i = blockIdx.x * TPB + threadIdx.x;
    if (i < N_DIM) dd[i] = dpx[i] + (double)dq[i];
}
__global__ __launch_bounds__(TPB) void k_dd_m(const float* db, double* dd) {
    int j = blockIdx.x * TPB + threadIdx.x;
    if (j < M_DIM) dd[N_DIM + j] += (double)db[j];
}
__global__ __launch_bounds__(64) void k_dd_t(double* sc, double* dd) {
    if (threadIdx.x == 0) dd[NMSUM] = -sc[1] - sc[2] - sc[3];
}
__global__ __launch_bounds__(TPB) void k_neg(double* dd) {
    int i = blockIdx.x * TPB + threadIdx.x;
    if (i < NM1) dd[i] = -dd[i];
}
__global__ __launch_bounds__(TPB) void k_ft_n(const double* c3, const double* W, double* U) {
    int i = blockIdx.x * TPB + threadIdx.x;
    if (i < N_DIM) U[i] = U[i] - c3[i] * W[NMSUM];
}
__global__ __launch_bounds__(TPB) void k_ft_m(const double* mask_d, const float* b,
                                              const double* tm, const double* W, double* U) {
    int j = blockIdx.x * TPB + threadIdx.x;
    if (j < M_DIM) {
        double wt = W[NMSUM];
        double tmv = tm[j] - (double)b[j] * wt;
        double wm = W[N_DIM + j];
        U[N_DIM + j] = mask_d[j] * (tmv - wm) + wm;
    }
}
__global__ __launch_bounds__(64) void k_ft_t(const double* e1, const double* e2, const double* xtpx,
                                             const double* W, double* U) {
    if (threadIdx.x == 0) U[NMSUM] = (*e1) + (*e2) + (*xtpx) * W[NMSUM];
}
__global__ __launch_bounds__(TPB) void k_cginit(const double* r, double* p, double* gam0) {
    int i = blockIdx.x * TPB + threadIdx.x;
    double loc = 0.0;
    if (i < NM1) { double v = r[i]; p[i] = v; loc = v * v; }
    blk_red_add(loc, gam0);
}

// ---------------- fused per-iteration kernels (4 launches/iter) ----------------
// K1: p-update + um + d1 = c3.p_n, d2 = b.um
__global__ __launch_bounds__(TPB) void k_iterA(const double* r, double* p,
                                               const double* mask_d, const double* c3,
                                               const float* b, double* um,
                                               double* sc, int it) {
    long i = (long)blockIdx.x * TPB + threadIdx.x;
    double* gam = sc + 432;
    double* base = sc + 16 + 8 * it;
    double l1 = 0.0, l2 = 0.0;
    if (i < NM1) {
        double pn;
        if (it > 0) {
            double beta = gam[it] / gam[it - 1];
            pn = r[i] + beta * p[i];
            p[i] = pn;
        } else {
            pn = p[i];
        }
        if (i < N_DIM) {
            l1 = c3[i] * pn;
        } else if (i < NMSUM) {
            int j = (int)(i - N_DIM);
            double u = mask_d[j] * pn;
            um[j] = u;
            l2 = (double)b[j] * u;
        }
    }
    blk_red_add(l1, base);       // d1
    blk_red_add(l2, base + 1);   // d2
}

// K2: Fmv — quad-per-row CSR gathers + elementwise finish + e1,e2 dots
__global__ __launch_bounds__(TPB) void k_fmv(const int* __restrict__ rptrP, const int2* __restrict__ pP,
                                             const int* __restrict__ rptrAc, const int2* __restrict__ pAc,
                                             const int* __restrict__ rptrAr, const int2* __restrict__ pAr,
                                             const float* __restrict__ q, const float* __restrict__ b,
                                             const double* __restrict__ p, const double* __restrict__ um,
                                             double* __restrict__ Fp, double* sc, int it) {
    long t = (long)blockIdx.x * TPB + threadIdx.x;
    long qd = t >> 2;
    int lane = (int)(t & 3);
    double* base = sc + 16 + 8 * it;
    double ut = p[NMSUM];
    double l1 = 0.0, l2 = 0.0;
    if (qd < N_DIM) {
        int i = (int)qd;
        double s = row_dot_quad(pP, rptrP[i], rptrP[i + 1], p, lane)
                 + row_dot_quad(pAc, rptrAc[i], rptrAc[i + 1], um, lane);
        if (lane == 0) {
            double r1 = s + (double)q[i] * ut;
            double v = (r1 - p[i]) + p[i];
            Fp[i] = v;
            l1 = (double)q[i] * v;
        }
    } else if (qd < NMSUM) {
        int j = (int)(qd - N_DIM);
        double s = row_dot_quad(pAr, rptrAr[j], rptrAr[j + 1], p, lane);
        if (lane == 0) {
            double r2 = -s + (double)b[j] * ut;
            double v = (r2 - um[j]) + p[N_DIM + j];
            Fp[N_DIM + j] = v;
            l2 = (double)b[j] * v;
        }
    } else if (qd == NMSUM && lane == 0) {
        double r3 = -base[0] - base[1] + sc[0] * ut;
        Fp[NMSUM] = (r3 - ut) + ut;
    }
    blk_red_add(l1, base + 2);   // e1
    blk_red_add(l2, base + 3);   // e2
}

// K3: FTmv — quad-per-row CSR gathers + elementwise finish + pq dot
__global__ __launch_bounds__(TPB) void k_ftmv(const int* __restrict__ rptrP, const int2* __restrict__ pP,
                                              const int* __restrict__ rptrAc, const int2* __restrict__ pAc,
                                              const int* __restrict__ rptrAr, const int2* __restrict__ pAr,
                                              const float* __restrict__ b, const double* __restrict__ mask_d,
                                              const double* __restrict__ c3,
                                              const double* __restrict__ Fp, const double* __restrict__ p,
                                              double* __restrict__ Ap, double* sc, int it) {
    long t = (long)blockIdx.x * TPB + threadIdx.x;
    long qd = t >> 2;
    int lane = (int)(t & 3);
    double* base = sc + 16 + 8 * it;
    double wt = Fp[NMSUM];
    double l = 0.0;
    if (qd < N_DIM) {
        int i = (int)qd;
        double s = row_dot_quad(pP, rptrP[i], rptrP[i + 1], Fp, lane)
                 - row_dot_quad(pAc, rptrAc[i], rptrAc[i + 1], Fp + N_DIM, lane);
        if (lane == 0) {
            double v = s - c3[i] * wt;
            Ap[i] = v;
            l = p[i] * v;
        }
    } else if (qd < NMSUM) {
        int j = (int)(qd - N_DIM);
        double s = row_dot_quad(pAr, rptrAr[j], rptrAr[j + 1], Fp, lane);
        if (lane == 0) {
            double tmv = s - (double)b[j] * wt;
            double wm = Fp[N_DIM + j];
            double v = mask_d[j] * (tmv - wm) + wm;
            Ap[N_DIM + j] = v;
            l = p[N_DIM + j] * v;
        }
    } else if (qd == NMSUM && lane == 0) {
        double tt = base[2] + base[3] + sc[0] * wt;
        Ap[NMSUM] = tt;
        l = p[NMSUM] * tt;
    }
    blk_red_add(l, base + 4);   // pq
}

// K4: x,r update + gam[it+1]
__global__ __launch_bounds__(TPB) void k_upd(const double* p, const double* Ap,
                                             double* xcg, double* r, double* sc, int it) {
    long i = (long)blockIdx.x * TPB + threadIdx.x;
    double* gam = sc + 432;
    double* base = sc + 16 + 8 * it;
    double alpha = gam[it] / base[4];
    double l = 0.0;
    if (i < NM1) {
        xcg[i] += alpha * p[i];
        double rn = r[i] - alpha * Ap[i];
        r[i] = rn;
        l = rn * rn;
    }
    blk_red_add(l, &gam[it + 1]);
}

__global__ __launch_bounds__(TPB) void k_final(const double* xcg, const double* mask_d,
                                               const float* x, const float* y, const float* s,
                                               float* out) {
    int i = blockIdx.x * TPB + threadIdx.x;
    double dzt = xcg[NMSUM];
    if (i < N_DIM) {
        out[i] = (float)(xcg[i] - (double)x[i] * dzt);
    } else if (i < NMSUM) {
        int j = i - N_DIM;
        double dzm = xcg[N_DIM + j];
        double t = mask_d[j] * dzm;
        out[N_DIM + j] = (float)(t - (double)y[j] * dzt);
        out[N_DIM + M_DIM + j] = (float)(t - dzm - (double)s[j] * dzt);
    }
}

extern "C" void kernel_launch(void* const* d_in, const int* in_sizes, int n_in,
                              void* d_out, int out_size, void* d_ws, size_t ws_size,
                              hipStream_t stream) {
    const int*   Pr  = (const int*)d_in[0];
    const int*   Pc  = (const int*)d_in[1];
    const float* Pv  = (const float*)d_in[2];
    const int*   Ar  = (const int*)d_in[3];
    const int*   Ac  = (const int*)d_in[4];
    const float* Av  = (const float*)d_in[5];
    const float* q   = (const float*)d_in[6];
    const float* b   = (const float*)d_in[7];
    const float* x   = (const float*)d_in[8];
    const float* yv  = (const float*)d_in[9];
    const float* sv  = (const float*)d_in[10];
    const float* dPv = (const float*)d_in[11];
    const float* dAv = (const float*)d_in[12];
    const float* dq  = (const float*)d_in[13];
    const float* db  = (const float*)d_in[14];
    float* out = (float*)d_out;

    char* wp = (char*)d_ws;
    auto alloc = [&](size_t bytes) { char* r0 = wp; wp += (bytes + 255) & ~255ull; return r0; };

    double* sc     = (double*)alloc(NSLOT * 8);
    double* mask_d = (double*)alloc((size_t)M_DIM * 8);
    double* pim_d  = (double*)alloc((size_t)M_DIM * 8);
    double* xd     = (double*)alloc((size_t)N_DIM * 8);
    double* Px     = (double*)alloc((size_t)N_DIM * 8);
    double* dpx    = (double*)alloc((size_t)N_DIM * 8);
    double* c3     = (double*)alloc((size_t)N_DIM * 8);
    double* um     = (double*)alloc((size_t)M_DIM * 8);
    double* tm     = (double*)alloc((size_t)M_DIM * 8);
    double* dd     = (double*)alloc((size_t)NM1 * 8);
    double* r      = (double*)alloc((size_t)NM1 * 8);
    double* p      = (double*)alloc((size_t)NM1 * 8);
    double* xcg    = (double*)alloc((size_t)NM1 * 8);
    double* Fp     = (double*)alloc((size_t)NM1 * 8);
    double* Ap     = (double*)alloc((size_t)NM1 * 8);
    int2*  pAr    = (int2*)alloc((size_t)NNZ_A * 8);
    int2*  pAc    = (int2*)alloc((size_t)NNZ_A * 8);
    int2*  pP     = (int2*)alloc((size_t)NNZ_P * 8);
    float* dvalAr = (float*)alloc((size_t)NNZ_A * 4);
    float* dvalAc = (float*)alloc((size_t)NNZ_A * 4);
    float* dvalP  = (float*)alloc((size_t)NNZ_P * 4);
    int*   rptrAr = (int*)alloc((size_t)(M_DIM + 1) * 4);
    int*   rptrAc = (int*)alloc((size_t)(N_DIM + 1) * 4);
    int*   rptrP  = (int*)alloc((size_t)(N_DIM + 1) * 4);
    int*   cntR   = (int*)alloc((size_t)M_DIM * 4);   // reused as cursor
    int*   cntC   = (int*)alloc((size_t)N_DIM * 4);
    int*   cntP   = (int*)alloc((size_t)N_DIM * 4);
    int*   blks   = (int*)alloc(1024 * 4);

    double* xtpx = sc + 0;
    double* gam  = sc + 432;

    auto g = [](long n) { return dim3((unsigned)((n + TPB - 1) / TPB)); };

    // ---- CSR build ----
    hipLaunchKernelGGL(k_init, g(NM1), dim3(TPB), 0, stream, sc, yv, sv, x, mask_d, pim_d, xd, xcg, cntR, cntC, cntP);
    hipLaunchKernelGGL(k_hist, g(NNZ_A), dim3(TPB), 0, stream, Ar, Ac, Pr, cntR, cntC, cntP);

    auto scan = [&](int* cnt, int len, int* rptr) {
        int nb = (len + TPB - 1) / TPB;
        hipLaunchKernelGGL(k_scan1, dim3((unsigned)nb), dim3(TPB), 0, stream, cnt, len, rptr, blks);
        hipLaunchKernelGGL(k_scan2, dim3(1), dim3(1024), 0, stream, blks, nb, rptr + len);
        hipLaunchKernelGGL(k_scan3, dim3((unsigned)nb), dim3(TPB), 0, stream, rptr, blks, len, cnt);
    };
    scan(cntR, M_DIM, rptrAr);   // cntR becomes cursor
    scan(cntC, N_DIM, rptrAc);
    scan(cntP, N_DIM, rptrP);

    hipLaunchKernelGGL(k_fillAr, g(NNZ_A), dim3(TPB), 0, stream, Ar, Ac, Av, dAv, cntR, pAr, dvalAr);
    hipLaunchKernelGGL(k_fillAc, g(NNZ_A), dim3(TPB), 0, stream, Ar, Ac, Av, dAv, cntC, pAc, dvalAc);
    hipLaunchKernelGGL(k_fillP,  g(NNZ_P), dim3(TPB), 0, stream, Pr, Pc, Pv, dPv, cntP, pP, dvalP);

    // ---- setup math ----
    hipLaunchKernelGGL(k_csr, g(N_DIM), dim3(TPB), 0, stream, rptrP, pP, xd, Px, 1.0, 0, N_DIM);          // Px = P x
    hipLaunchKernelGGL(k_dot_fd, g(N_DIM), dim3(TPB), 0, stream, x, Px, (long)N_DIM, xtpx);
    hipLaunchKernelGGL(k_c3e, g(N_DIM), dim3(TPB), 0, stream, q, Px, c3);
    hipLaunchKernelGGL(k_csr_d, g(N_DIM), dim3(TPB), 0, stream, rptrP, pP, dvalP, xd, dpx, 1.0, 0, N_DIM); // dpx = dP x
    hipLaunchKernelGGL(k_dd_n, g(N_DIM), dim3(TPB), 0, stream, dpx, dq, dd);
    hipLaunchKernelGGL(k_csr_d, g(N_DIM), dim3(TPB), 0, stream, rptrAc, pAc, dvalAc, pim_d, dd, 1.0, 1, N_DIM);   // += dA^T pim
    hipLaunchKernelGGL(k_csr_d, g(M_DIM), dim3(TPB), 0, stream, rptrAr, pAr, dvalAr, xd, dd + N_DIM, -1.0, 0, M_DIM); // -dA x
    hipLaunchKernelGGL(k_dd_m, g(M_DIM), dim3(TPB), 0, stream, db, dd);
    hipLaunchKernelGGL(k_dot_ff, g(N_DIM), dim3(TPB), 0, stream, dq, x, (long)N_DIM, sc + 1);
    hipLaunchKernelGGL(k_dot_fd, g(M_DIM), dim3(TPB), 0, stream, db, pim_d, (long)M_DIM, sc + 2);
    hipLaunchKernelGGL(k_dot_fd, g(N_DIM), dim3(TPB), 0, stream, x, dpx, (long)N_DIM, sc + 3);
    hipLaunchKernelGGL(k_dd_t, dim3(1), dim3(64), 0, stream, sc, dd);
    hipLaunchKernelGGL(k_neg, g(NM1), dim3(TPB), 0, stream, dd);
    hipLaunchKernelGGL(k_csr, g(N_DIM), dim3(TPB), 0, stream, rptrP, pP, dd, r, 1.0, 0, N_DIM);            // r_n = P wn
    hipLaunchKernelGGL(k_csr, g(N_DIM), dim3(TPB), 0, stream, rptrAc, pAc, dd + N_DIM, r, -1.0, 1, N_DIM); // -= A^T wm
    hipLaunchKernelGGL(k_ft_n, g(N_DIM), dim3(TPB), 0, stream, c3, dd, r);
    hipLaunchKernelGGL(k_csr, g(M_DIM), dim3(TPB), 0, stream, rptrAr, pAr, dd, tm, 1.0, 0, M_DIM);         // tm = A wn
    hipLaunchKernelGGL(k_ft_m, g(M_DIM), dim3(TPB), 0, stream, mask_d, b, tm, dd, r);
    hipLaunchKernelGGL(k_dot_fd, g(N_DIM), dim3(TPB), 0, stream, q, dd, (long)N_DIM, sc + 8);
    hipLaunchKernelGGL(k_dot_fd, g(M_DIM), dim3(TPB), 0, stream, b, dd + N_DIM, (long)M_DIM, sc + 9);
    hipLaunchKernelGGL(k_ft_t, dim3(1), dim3(64), 0, stream, sc + 8, sc + 9, xtpx, dd, r);
    hipLaunchKernelGGL(k_cginit, g(NM1), dim3(TPB), 0, stream, r, p, gam);

    // ---- 20 CG iterations, 4 fused launches each (SpMVs quad-per-row) ----
    for (int it = 0; it < CG_ITERS; ++it) {
        hipLaunchKernelGGL(k_iterA, g(NM1), dim3(TPB), 0, stream, r, p, mask_d, c3, b, um, sc, it);
        hipLaunchKernelGGL(k_fmv,   g(4L * NM1), dim3(TPB), 0, stream, rptrP, pP, rptrAc, pAc, rptrAr, pAr,
                           q, b, p, um, Fp, sc, it);
        hipLaunchKernelGGL(k_ftmv,  g(4L * NM1), dim3(TPB), 0, stream, rptrP, pP, rptrAc, pAc, rptrAr, pAr,
                           b, mask_d, c3, Fp, p, Ap, sc, it);
        hipLaunchKernelGGL(k_upd,   g(NM1), dim3(TPB), 0, stream, p, Ap, xcg, r, sc, it);
    }

    hipLaunchKernelGGL(k_final, g(NMSUM), dim3(TPB), 0, stream, xcg, mask_d, x, yv, sv, out);
}

// Round 7
// 3658.710 us; speedup vs baseline: 3.2839x; 1.6025x over previous
//
#include <hip/hip_runtime.h>

#define N_DIM 100000
#define M_DIM 200000
#define NNZ_A 2000000
#define NNZ_P 500000
#define NNZ_GN (NNZ_A + NNZ_P)
#define NMSUM 300000
#define NM1   300001
#define CG_ITERS 20
#define TPB 256
#define NSLOT 512

// slots: sc[0]=xTPx, sc[1..3]=dd_t dots, sc[8..9]=rhs-FTmv dots,
// per-iter base 16+8*it: {d1,d2,e1,e2,pq,ftau}, gam[] at sc+432 (0..50)

__device__ __forceinline__ void blk_red_add(double v, double* dst) {
    __shared__ double sb[TPB];
    int tid = threadIdx.x;
    __syncthreads();
    sb[tid] = v;
    __syncthreads();
    for (int sh = TPB / 2; sh > 0; sh >>= 1) {
        if (tid < sh) sb[tid] += sb[tid + sh];
        __syncthreads();
    }
    if (tid == 0) atomicAdd(dst, sb[0]);
}

// 8/4/1 unrolled CSR row gather (thread-per-row)
__device__ __forceinline__ double row_dot8(const int2* __restrict__ pair, int beg, int end,
                                           const double* __restrict__ vin) {
    double s = 0.0;
    int k = beg;
    for (; k + 8 <= end; k += 8) {
        int2 a0 = pair[k],     a1 = pair[k + 1], a2 = pair[k + 2], a3 = pair[k + 3];
        int2 a4 = pair[k + 4], a5 = pair[k + 5], a6 = pair[k + 6], a7 = pair[k + 7];
        double g0 = vin[a0.x], g1 = vin[a1.x], g2 = vin[a2.x], g3 = vin[a3.x];
        double g4 = vin[a4.x], g5 = vin[a5.x], g6 = vin[a6.x], g7 = vin[a7.x];
        s += (double)__int_as_float(a0.y) * g0;
        s += (double)__int_as_float(a1.y) * g1;
        s += (double)__int_as_float(a2.y) * g2;
        s += (double)__int_as_float(a3.y) * g3;
        s += (double)__int_as_float(a4.y) * g4;
        s += (double)__int_as_float(a5.y) * g5;
        s += (double)__int_as_float(a6.y) * g6;
        s += (double)__int_as_float(a7.y) * g7;
    }
    for (; k + 4 <= end; k += 4) {
        int2 a0 = pair[k], a1 = pair[k + 1], a2 = pair[k + 2], a3 = pair[k + 3];
        double g0 = vin[a0.x], g1 = vin[a1.x], g2 = vin[a2.x], g3 = vin[a3.x];
        s += (double)__int_as_float(a0.y) * g0;
        s += (double)__int_as_float(a1.y) * g1;
        s += (double)__int_as_float(a2.y) * g2;
        s += (double)__int_as_float(a3.y) * g3;
    }
    for (; k < end; ++k) {
        int2 a = pair[k];
        s += (double)__int_as_float(a.y) * vin[a.x];
    }
    return s;
}

__device__ __forceinline__ double row_dot4(const int2* __restrict__ pair, int beg, int end,
                                           const double* __restrict__ vin) {
    double s = 0.0;
    int k = beg;
    for (; k + 4 <= end; k += 4) {
        int2 a0 = pair[k], a1 = pair[k + 1], a2 = pair[k + 2], a3 = pair[k + 3];
        double g0 = vin[a0.x], g1 = vin[a1.x], g2 = vin[a2.x], g3 = vin[a3.x];
        s += (double)__int_as_float(a0.y) * g0;
        s += (double)__int_as_float(a1.y) * g1;
        s += (double)__int_as_float(a2.y) * g2;
        s += (double)__int_as_float(a3.y) * g3;
    }
    for (; k < end; ++k) {
        int2 a = pair[k];
        s += (double)__int_as_float(a.y) * vin[a.x];
    }
    return s;
}

__device__ __forceinline__ double row_dot_d(const int2* __restrict__ pair,
                                            const float* __restrict__ dval, int beg, int end,
                                            const double* __restrict__ vin) {
    double s = 0.0;
    int k = beg;
    for (; k + 4 <= end; k += 4) {
        int c0 = pair[k].x, c1 = pair[k + 1].x, c2 = pair[k + 2].x, c3v = pair[k + 3].x;
        float d0 = dval[k], d1 = dval[k + 1], d2 = dval[k + 2], d3 = dval[k + 3];
        double g0 = vin[c0], g1 = vin[c1], g2 = vin[c2], g3 = vin[c3v];
        s += (double)d0 * g0;
        s += (double)d1 * g1;
        s += (double)d2 * g2;
        s += (double)d3 * g3;
    }
    for (; k < end; ++k)
        s += (double)dval[k] * vin[pair[k].x];
    return s;
}

// ---------------- setup: init + histogram + scan + fill ----------------
__global__ __launch_bounds__(TPB) void k_init(double* sc, const float* y, const float* s,
                                              const float* x, double* mask_d, double* xpim,
                                              double* xcg,
                                              int* nP, int* cntGn, int* cntAr) {
    long i = (long)blockIdx.x * TPB + threadIdx.x;
    if (i < NSLOT) sc[i] = 0.0;
    if (i < M_DIM) {
        double v = (double)y[i] - (double)s[i];
        mask_d[i] = v > 0.0 ? 1.0 : 0.0;
        xpim[N_DIM + i] = v > 0.0 ? v : 0.0;   // pi_m
        cntAr[i] = 0;
    }
    if (i < N_DIM) {
        xpim[i] = (double)x[i];
        nP[i] = 0; cntGn[i] = 0;
    }
    if (i < NM1) xcg[i] = 0.0;
}

__global__ __launch_bounds__(TPB) void k_hist(const int* Ar, const int* Ac, const int* Pr,
                                              int* nP, int* cntGn, int* cntAr) {
    long k = (long)blockIdx.x * TPB + threadIdx.x;
    if (k < NNZ_A) {
        atomicAdd(&cntGn[Ac[k]], 1);
        atomicAdd(&cntAr[Ar[k]], 1);
    }
    if (k < NNZ_P) atomicAdd(&nP[Pr[k]], 1);
}

__global__ __launch_bounds__(TPB) void k_comb(const int* nP, int* cntGn) {
    int i = blockIdx.x * TPB + threadIdx.x;
    if (i < N_DIM) cntGn[i] += nP[i];
}

__global__ __launch_bounds__(TPB) void k_scan1(const int* cnt, int len, int* exc, int* blksum) {
    __shared__ int sb[TPB];
    int i = blockIdx.x * TPB + threadIdx.x;
    int v = (i < len) ? cnt[i] : 0;
    sb[threadIdx.x] = v;
    __syncthreads();
    for (int sh = 1; sh < TPB; sh <<= 1) {
        int t = (threadIdx.x >= sh) ? sb[threadIdx.x - sh] : 0;
        __syncthreads();
        sb[threadIdx.x] += t;
        __syncthreads();
    }
    if (i < len) exc[i] = sb[threadIdx.x] - v;
    if (threadIdx.x == TPB - 1) blksum[blockIdx.x] = sb[TPB - 1];
}

__global__ __launch_bounds__(1024) void k_scan2(int* blksum, int nb, int* total_out) {
    __shared__ int sb[1024];
    int t = threadIdx.x;
    int v = (t < nb) ? blksum[t] : 0;
    sb[t] = v;
    __syncthreads();
    for (int sh = 1; sh < 1024; sh <<= 1) {
        int x = (t >= sh) ? sb[t - sh] : 0;
        __syncthreads();
        sb[t] += x;
        __syncthreads();
    }
    if (t < nb) blksum[t] = sb[t] - v;          // exclusive block offsets
    if (t == nb - 1) *total_out = sb[t];        // rptr[len] = total
}

__global__ __launch_bounds__(TPB) void k_scan3(int* exc, const int* blksum, int len, int* cur) {
    int i = blockIdx.x * TPB + threadIdx.x;
    if (i < len) {
        int v = exc[i] + blksum[blockIdx.x];
        exc[i] = v;
        cur[i] = v;
    }
}

// fills: P entries FIRST per G_n row (prefix nP[i]), then A^T entries; Ar separate
__global__ __launch_bounds__(TPB) void k_fillGnP(const int* Pr, const int* Pc, const float* Pv,
                                                 const float* dPv, int* curGn,
                                                 int2* pGn, float* dvalGn) {
    long k = (long)blockIdx.x * TPB + threadIdx.x;
    if (k < NNZ_P) {
        int pos = atomicAdd(&curGn[Pr[k]], 1);
        pGn[pos] = make_int2(Pc[k], __float_as_int(Pv[k]));
        dvalGn[pos] = dPv[k];
    }
}
__global__ __launch_bounds__(TPB) void k_fillGnA(const int* Ar, const int* Ac, const float* Av,
                                                 const float* dAv, int* curGn,
                                                 int2* pGn, float* dvalGn) {
    long k = (long)blockIdx.x * TPB + threadIdx.x;
    if (k < NNZ_A) {
        int pos = atomicAdd(&curGn[Ac[k]], 1);
        pGn[pos] = make_int2(N_DIM + Ar[k], __float_as_int(Av[k]));
        dvalGn[pos] = dAv[k];
    }
}
__global__ __launch_bounds__(TPB) void k_fillAr(const int* Ar, const int* Ac, const float* Av,
                                                const float* dAv, int* curAr,
                                                int2* pAr, float* dvalAr) {
    long k = (long)blockIdx.x * TPB + threadIdx.x;
    if (k < NNZ_A) {
        int pos = atomicAdd(&curAr[Ar[k]], 1);
        pAr[pos] = make_int2(Ac[k], __float_as_int(Av[k]));
        dvalAr[pos] = dAv[k];
    }
}

// fused: Px, dpx, c3, dd_n (P entries are the nP-prefix of each G_n row)
__global__ __launch_bounds__(TPB) void k_setup_n(const int* __restrict__ rptrGn,
                                                 const int2* __restrict__ pGn,
                                                 const float* __restrict__ dvalGn,
                                                 const int* __restrict__ nP,
                                                 const double* __restrict__ xpim,
                                                 const float* __restrict__ q,
                                                 const float* __restrict__ dq,
                                                 double* Px, double* dpx, double* c3, double* dd) {
    int i = blockIdx.x * TPB + threadIdx.x;
    if (i >= N_DIM) return;
    int beg = rptrGn[i], end = rptrGn[i + 1];
    int np = nP[i];
    double px = 0.0, dpxv = 0.0, sa = 0.0;
    for (int k = beg; k < end; ++k) {
        int2 e = pGn[k];
        float dv = dvalGn[k];
        double g = xpim[e.x];
        if (k - beg < np) {
            px += (double)__int_as_float(e.y) * g;
            dpxv += (double)dv * g;
        } else {
            sa += (double)dv * g;
        }
    }
    Px[i] = px;
    dpx[i] = dpxv;
    c3[i] = (double)q[i] + 2.0 * px;
    dd[i] = dpxv + sa + (double)dq[i];
}

// fused: dd_m = -(dA x) + db
__global__ __launch_bounds__(TPB) void k_setup_m(const int* __restrict__ rptrAr,
                                                 const int2* __restrict__ pAr,
                                                 const float* __restrict__ dvalAr,
                                                 const double* __restrict__ xpim,
                                                 const float* __restrict__ db, double* dd) {
    int j = blockIdx.x * TPB + threadIdx.x;
    if (j >= M_DIM) return;
    double s = row_dot_d(pAr, dvalAr, rptrAr[j], rptrAr[j + 1], xpim);
    dd[N_DIM + j] = -s + (double)db[j];
}

// ---------------- dots & small elementwise ----------------
__global__ __launch_bounds__(TPB) void k_dot_fd(const float* a, const double* b, long len, double* dst) {
    long i = (long)blockIdx.x * TPB + threadIdx.x;
    double loc = 0.0;
    if (i < len) loc = (double)a[i] * b[i];
    blk_red_add(loc, dst);
}
__global__ __launch_bounds__(TPB) void k_dot_ff(const float* a, const float* b, long len, double* dst) {
    long i = (long)blockIdx.x * TPB + threadIdx.x;
    double loc = 0.0;
    if (i < len) loc = (double)a[i] * (double)b[i];
    blk_red_add(loc, dst);
}
__global__ __launch_bounds__(64) void k_dd_t(double* sc, double* dd) {
    if (threadIdx.x == 0) dd[NMSUM] = -sc[1] - sc[2] - sc[3];
}
// dd = -dd ; WC = [W_n ; -W_m]
__global__ __launch_bounds__(TPB) void k_negWC(double* dd, double* WC) {
    int i = blockIdx.x * TPB + threadIdx.x;
    if (i < NM1) {
        double nv = -dd[i];
        dd[i] = nv;
        if (i < N_DIM) WC[i] = nv;
        else if (i < NMSUM) WC[i] = -nv;
    }
}
__global__ __launch_bounds__(TPB) void k_rn(const int* __restrict__ rptrGn, const int2* __restrict__ pGn,
                                            const double* __restrict__ WC,
                                            const double* __restrict__ c3,
                                            const double* __restrict__ dd, double* r) {
    int i = blockIdx.x * TPB + threadIdx.x;
    if (i >= N_DIM) return;
    double s = row_dot8(pGn, rptrGn[i], rptrGn[i + 1], WC);   // P wn - A^T wm
    r[i] = s - c3[i] * dd[NMSUM];
}
__global__ __launch_bounds__(TPB) void k_rm(const int* __restrict__ rptrAr, const int2* __restrict__ pAr,
                                            const double* __restrict__ WC,
                                            const double* __restrict__ mask_d,
                                            const float* __restrict__ b,
                                            const double* __restrict__ dd, double* r) {
    int j = blockIdx.x * TPB + threadIdx.x;
    if (j >= M_DIM) return;
    double s = row_dot4(pAr, rptrAr[j], rptrAr[j + 1], WC);   // A wn
    double wt = dd[NMSUM];
    double tmv = s - (double)b[j] * wt;
    double wm = dd[N_DIM + j];
    r[N_DIM + j] = mask_d[j] * (tmv - wm) + wm;
}
__global__ __launch_bounds__(64) void k_ft_t(const double* e1, const double* e2, const double* xtpx,
                                             const double* W, double* U) {
    if (threadIdx.x == 0) U[NMSUM] = (*e1) + (*e2) + (*xtpx) * W[NMSUM];
}
__global__ __launch_bounds__(TPB) void k_cginit(const double* r, double* p, double* gam0) {
    int i = blockIdx.x * TPB + threadIdx.x;
    double loc = 0.0;
    if (i < NM1) { double v = r[i]; p[i] = v; loc = v * v; }
    blk_red_add(loc, gam0);
}

// ---------------- fused per-iteration kernels (4 launches/iter) ----------------
// K1: p-update + pum=[p_n; um] + d1 = c3.p_n, d2 = b.um
__global__ __launch_bounds__(TPB) void k_iterA(const double* r, double* p,
                                               const double* mask_d, const double* c3,
                                               const float* b, double* pum,
                                               double* sc, int it) {
    long i = (long)blockIdx.x * TPB + threadIdx.x;
    double* gam = sc + 432;
    double* base = sc + 16 + 8 * it;
    double l1 = 0.0, l2 = 0.0;
    if (i < NM1) {
        double pn;
        if (it > 0) {
            double beta = gam[it] / gam[it - 1];
            pn = r[i] + beta * p[i];
            p[i] = pn;
        } else {
            pn = p[i];
        }
        if (i < N_DIM) {
            l1 = c3[i] * pn;
            pum[i] = pn;
        } else if (i < NMSUM) {
            int j = (int)(i - N_DIM);
            double u = mask_d[j] * pn;
            pum[i] = u;
            l2 = (double)b[j] * u;
        }
    }
    blk_red_add(l1, base);       // d1
    blk_red_add(l2, base + 1);   // d2
}

// K2: Fmv — merged G_n row dot over pum; writes Fpc=[v_n; -v_m], base[5]=F_tau; e1,e2
__global__ __launch_bounds__(TPB) void k_fmv(const int* __restrict__ rptrGn, const int2* __restrict__ pGn,
                                             const int* __restrict__ rptrAr, const int2* __restrict__ pAr,
                                             const float* __restrict__ q, const float* __restrict__ b,
                                             const double* __restrict__ p, const double* __restrict__ pum,
                                             double* __restrict__ Fpc, double* sc, int it) {
    long i = (long)blockIdx.x * TPB + threadIdx.x;
    double* base = sc + 16 + 8 * it;
    double ut = p[NMSUM];
    double l1 = 0.0, l2 = 0.0;
    if (i < N_DIM) {
        double s = row_dot8(pGn, rptrGn[i], rptrGn[i + 1], pum);   // P p + A^T um
        double r1 = s + (double)q[i] * ut;
        double v = (r1 - p[i]) + p[i];
        Fpc[i] = v;
        l1 = (double)q[i] * v;
    } else if (i < NMSUM) {
        int j = (int)(i - N_DIM);
        double s = row_dot4(pAr, rptrAr[j], rptrAr[j + 1], pum);   // A p_n
        double r2 = -s + (double)b[j] * ut;
        double v = (r2 - pum[i]) + p[i];
        Fpc[i] = -v;
        l2 = (double)b[j] * v;
    } else if (i == NMSUM) {
        double r3 = -base[0] - base[1] + sc[0] * ut;
        base[5] = (r3 - ut) + ut;                                  // F_tau
    }
    blk_red_add(l1, base + 2);   // e1
    blk_red_add(l2, base + 3);   // e2
}

// K3: FTmv — merged G_n row dot over Fpc; Ap + pq
__global__ __launch_bounds__(TPB) void k_ftmv(const int* __restrict__ rptrGn, const int2* __restrict__ pGn,
                                              const int* __restrict__ rptrAr, const int2* __restrict__ pAr,
                                              const float* __restrict__ b, const double* __restrict__ mask_d,
                                              const double* __restrict__ c3,
                                              const double* __restrict__ Fpc, const double* __restrict__ p,
                                              double* __restrict__ Ap, double* sc, int it) {
    long i = (long)blockIdx.x * TPB + threadIdx.x;
    double* base = sc + 16 + 8 * it;
    double wt = base[5];
    double l = 0.0;
    if (i < N_DIM) {
        double s = row_dot8(pGn, rptrGn[i], rptrGn[i + 1], Fpc);   // P Fp_n - A^T Fp_m
        double v = s - c3[i] * wt;
        Ap[i] = v;
        l = p[i] * v;
    } else if (i < NMSUM) {
        int j = (int)(i - N_DIM);
        double s = row_dot4(pAr, rptrAr[j], rptrAr[j + 1], Fpc);   // A Fp_n
        double tmv = s - (double)b[j] * wt;
        double wm = -Fpc[i];
        double v = mask_d[j] * (tmv - wm) + wm;
        Ap[i] = v;
        l = p[i] * v;
    } else if (i == NMSUM) {
        double tt = base[2] + base[3] + sc[0] * wt;
        Ap[i] = tt;
        l = p[i] * tt;
    }
    blk_red_add(l, base + 4);   // pq
}

// K4: x,r update + gam[it+1]
__global__ __launch_bounds__(TPB) void k_upd(const double* p, const double* Ap,
                                             double* xcg, double* r, double* sc, int it) {
    long i = (long)blockIdx.x * TPB + threadIdx.x;
    double* gam = sc + 432;
    double* base = sc + 16 + 8 * it;
    double alpha = gam[it] / base[4];
    double l = 0.0;
    if (i < NM1) {
        xcg[i] += alpha * p[i];
        double rn = r[i] - alpha * Ap[i];
        r[i] = rn;
        l = rn * rn;
    }
    blk_red_add(l, &gam[it + 1]);
}

__global__ __launch_bounds__(TPB) void k_final(const double* xcg, const double* mask_d,
                                               const float* x, const float* y, const float* s,
                                               float* out) {
    int i = blockIdx.x * TPB + threadIdx.x;
    double dzt = xcg[NMSUM];
    if (i < N_DIM) {
        out[i] = (float)(xcg[i] - (double)x[i] * dzt);
    } else if (i < NMSUM) {
        int j = i - N_DIM;
        double dzm = xcg[N_DIM + j];
        double t = mask_d[j] * dzm;
        out[N_DIM + j] = (float)(t - (double)y[j] * dzt);
        out[N_DIM + M_DIM + j] = (float)(t - dzm - (double)s[j] * dzt);
    }
}

extern "C" void kernel_launch(void* const* d_in, const int* in_sizes, int n_in,
                              void* d_out, int out_size, void* d_ws, size_t ws_size,
                              hipStream_t stream) {
    const int*   Pr  = (const int*)d_in[0];
    const int*   Pc  = (const int*)d_in[1];
    const float* Pv  = (const float*)d_in[2];
    const int*   Ar  = (const int*)d_in[3];
    const int*   Ac  = (const int*)d_in[4];
    const float* Av  = (const float*)d_in[5];
    const float* q   = (const float*)d_in[6];
    const float* b   = (const float*)d_in[7];
    const float* x   = (const float*)d_in[8];
    const float* yv  = (const float*)d_in[9];
    const float* sv  = (const float*)d_in[10];
    const float* dPv = (const float*)d_in[11];
    const float* dAv = (const float*)d_in[12];
    const float* dq  = (const float*)d_in[13];
    const float* db  = (const float*)d_in[14];
    float* out = (float*)d_out;

    char* wp = (char*)d_ws;
    auto alloc = [&](size_t bytes) { char* r0 = wp; wp += (bytes + 255) & ~255ull; return r0; };

    double* sc     = (double*)alloc(NSLOT * 8);
    double* mask_d = (double*)alloc((size_t)M_DIM * 8);
    double* xpim   = (double*)alloc((size_t)NMSUM * 8);   // [x ; pi_m]
    double* Px     = (double*)alloc((size_t)N_DIM * 8);
    double* dpx    = (double*)alloc((size_t)N_DIM * 8);
    double* c3     = (double*)alloc((size_t)N_DIM * 8);
    double* dd     = (double*)alloc((size_t)NM1 * 8);
    double* r      = (double*)alloc((size_t)NM1 * 8);
    double* p      = (double*)alloc((size_t)NM1 * 8);
    double* xcg    = (double*)alloc((size_t)NM1 * 8);
    double* Ap     = (double*)alloc((size_t)NM1 * 8);
    double* pum    = (double*)alloc((size_t)NMSUM * 8);   // [p_n ; um]
    double* Fpc    = (double*)alloc((size_t)NMSUM * 8);   // [Fp_n ; -Fp_m]
    double* WC     = (double*)alloc((size_t)NMSUM * 8);   // [W_n ; -W_m]
    int2*  pGn    = (int2*)alloc((size_t)NNZ_GN * 8);
    int2*  pAr    = (int2*)alloc((size_t)NNZ_A * 8);
    float* dvalGn = (float*)alloc((size_t)NNZ_GN * 4);
    float* dvalAr = (float*)alloc((size_t)NNZ_A * 4);
    int*   rptrGn = (int*)alloc((size_t)(N_DIM + 1) * 4);
    int*   rptrAr = (int*)alloc((size_t)(M_DIM + 1) * 4);
    int*   nP     = (int*)alloc((size_t)N_DIM * 4);
    int*   cntGn  = (int*)alloc((size_t)N_DIM * 4);   // becomes cursor after scan
    int*   cntAr  = (int*)alloc((size_t)M_DIM * 4);   // becomes cursor after scan
    int*   blks   = (int*)alloc(1024 * 4);

    double* xtpx = sc + 0;
    double* gam  = sc + 432;

    auto g = [](long n) { return dim3((unsigned)((n + TPB - 1) / TPB)); };

    // ---- CSR build ----
    hipLaunchKernelGGL(k_init, g(NM1), dim3(TPB), 0, stream, sc, yv, sv, x, mask_d, xpim, xcg,
                       nP, cntGn, cntAr);
    hipLaunchKernelGGL(k_hist, g(NNZ_A), dim3(TPB), 0, stream, Ar, Ac, Pr, nP, cntGn, cntAr);
    hipLaunchKernelGGL(k_comb, g(N_DIM), dim3(TPB), 0, stream, nP, cntGn);

    auto scan = [&](int* cnt, int len, int* rptr) {
        int nb = (len + TPB - 1) / TPB;
        hipLaunchKernelGGL(k_scan1, dim3((unsigned)nb), dim3(TPB), 0, stream, cnt, len, rptr, blks);
        hipLaunchKernelGGL(k_scan2, dim3(1), dim3(1024), 0, stream, blks, nb, rptr + len);
        hipLaunchKernelGGL(k_scan3, dim3((unsigned)nb), dim3(TPB), 0, stream, rptr, blks, len, cnt);
    };
    scan(cntGn, N_DIM, rptrGn);   // cntGn becomes cursor
    scan(cntAr, M_DIM, rptrAr);   // cntAr becomes cursor

    // P entries first (prefix), then A^T entries — sequential launches preserve the invariant
    hipLaunchKernelGGL(k_fillGnP, g(NNZ_P), dim3(TPB), 0, stream, Pr, Pc, Pv, dPv, cntGn, pGn, dvalGn);
    hipLaunchKernelGGL(k_fillGnA, g(NNZ_A), dim3(TPB), 0, stream, Ar, Ac, Av, dAv, cntGn, pGn, dvalGn);
    hipLaunchKernelGGL(k_fillAr,  g(NNZ_A), dim3(TPB), 0, stream, Ar, Ac, Av, dAv, cntAr, pAr, dvalAr);

    // ---- setup math ----
    hipLaunchKernelGGL(k_setup_n, g(N_DIM), dim3(TPB), 0, stream, rptrGn, pGn, dvalGn, nP,
                       xpim, q, dq, Px, dpx, c3, dd);
    hipLaunchKernelGGL(k_setup_m, g(M_DIM), dim3(TPB), 0, stream, rptrAr, pAr, dvalAr, xpim, db, dd);
    hipLaunchKernelGGL(k_dot_fd, g(N_DIM), dim3(TPB), 0, stream, x, Px, (long)N_DIM, xtpx);
    hipLaunchKernelGGL(k_dot_ff, g(N_DIM), dim3(TPB), 0, stream, dq, x, (long)N_DIM, sc + 1);
    hipLaunchKernelGGL(k_dot_fd, g(M_DIM), dim3(TPB), 0, stream, db, xpim + N_DIM, (long)M_DIM, sc + 2);
    hipLaunchKernelGGL(k_dot_fd, g(N_DIM), dim3(TPB), 0, stream, x, dpx, (long)N_DIM, sc + 3);
    hipLaunchKernelGGL(k_dd_t, dim3(1), dim3(64), 0, stream, sc, dd);
    hipLaunchKernelGGL(k_negWC, g(NM1), dim3(TPB), 0, stream, dd, WC);
    hipLaunchKernelGGL(k_rn, g(N_DIM), dim3(TPB), 0, stream, rptrGn, pGn, WC, c3, dd, r);
    hipLaunchKernelGGL(k_rm, g(M_DIM), dim3(TPB), 0, stream, rptrAr, pAr, WC, mask_d, b, dd, r);
    hipLaunchKernelGGL(k_dot_fd, g(N_DIM), dim3(TPB), 0, stream, q, dd, (long)N_DIM, sc + 8);
    hipLaunchKernelGGL(k_dot_fd, g(M_DIM), dim3(TPB), 0, stream, b, dd + N_DIM, (long)M_DIM, sc + 9);
    hipLaunchKernelGGL(k_ft_t, dim3(1), dim3(64), 0, stream, sc + 8, sc + 9, xtpx, dd, r);
    hipLaunchKernelGGL(k_cginit, g(NM1), dim3(TPB), 0, stream, r, p, gam);

    // ---- 20 CG iterations, 4 fused launches each ----
    for (int it = 0; it < CG_ITERS; ++it) {
        hipLaunchKernelGGL(k_iterA, g(NM1), dim3(TPB), 0, stream, r, p, mask_d, c3, b, pum, sc, it);
        hipLaunchKernelGGL(k_fmv,   g(NM1), dim3(TPB), 0, stream, rptrGn, pGn, rptrAr, pAr,
                           q, b, p, pum, Fpc, sc, it);
        hipLaunchKernelGGL(k_ftmv,  g(NM1), dim3(TPB), 0, stream, rptrGn, pGn, rptrAr, pAr,
                           b, mask_d, c3, Fpc, p, Ap, sc, it);
        hipLaunchKernelGGL(k_upd,   g(NM1), dim3(TPB), 0, stream, p, Ap, xcg, r, sc, it);
    }

    hipLaunchKernelGGL(k_final, g(NMSUM), dim3(TPB), 0, stream, xcg, mask_d, x, yv, sv, out);
}

// Round 8
// 2525.870 us; speedup vs baseline: 4.7567x; 1.4485x over previous
//
#include <hip/hip_runtime.h>

#define N_DIM 100000
#define M_DIM 200000
#define NNZ_A 2000000
#define NNZ_P 500000
#define NNZ_GN (NNZ_A + NNZ_P)
#define NMSUM 300000
#define NM1   300001
#define CG_ITERS 20
#define TPB 256
#define NSLOT 512
#define REDSZ (20 * 5 * 64 + 21 * 64)   // per-iter {d1,d2,e1,e2,pq}[64] + gam[21][64]

// sc[0]=xTPx, sc[1..3]=dd_t dots, sc[8..9]=rhs dots, sc[16+it]=F_tau per iter

__device__ __forceinline__ void blk_red_add(double v, double* dst) {
    __shared__ double sb[TPB];
    int tid = threadIdx.x;
    __syncthreads();
    sb[tid] = v;
    __syncthreads();
    for (int sh = TPB / 2; sh > 0; sh >>= 1) {
        if (tid < sh) sb[tid] += sb[tid + sh];
        __syncthreads();
    }
    if (tid == 0) atomicAdd(dst, sb[0]);
}

// sum 64 slots, broadcast to all threads of the block (wave0 shuffle + LDS scalar)
__device__ __forceinline__ double blk_sum64w(const double* src) {
    __shared__ double bsh;
    int t = threadIdx.x;
    if (t < 64) {
        double v = src[t];
        v += __shfl_xor(v, 32); v += __shfl_xor(v, 16); v += __shfl_xor(v, 8);
        v += __shfl_xor(v, 4);  v += __shfl_xor(v, 2);  v += __shfl_xor(v, 1);
        if (t == 0) bsh = v;
    }
    __syncthreads();
    double r = bsh;
    __syncthreads();
    return r;
}

// 2-pair int4 row dot (rows padded to even length; pad = {0, 0.0f} -> +0.0)
__device__ __forceinline__ double row_dotx4(const int4* __restrict__ pp, int b2, int e2,
                                            const double* __restrict__ vin) {
    double s = 0.0;
    int k = b2;
    for (; k + 4 <= e2; k += 4) {
        int4 a = pp[k], b = pp[k + 1], c = pp[k + 2], d = pp[k + 3];
        double g0 = vin[a.x], g1 = vin[a.z], g2 = vin[b.x], g3 = vin[b.z];
        double g4 = vin[c.x], g5 = vin[c.z], g6 = vin[d.x], g7 = vin[d.z];
        s += (double)__int_as_float(a.y) * g0;
        s += (double)__int_as_float(a.w) * g1;
        s += (double)__int_as_float(b.y) * g2;
        s += (double)__int_as_float(b.w) * g3;
        s += (double)__int_as_float(c.y) * g4;
        s += (double)__int_as_float(c.w) * g5;
        s += (double)__int_as_float(d.y) * g6;
        s += (double)__int_as_float(d.w) * g7;
    }
    for (; k < e2; ++k) {
        int4 a = pp[k];
        s += (double)__int_as_float(a.y) * vin[a.x];
        s += (double)__int_as_float(a.w) * vin[a.z];
    }
    return s;
}

// scalar int2 row dots for setup (pads are zero-valued -> exact)
__device__ __forceinline__ double row_dot8(const int2* __restrict__ pair, int beg, int end,
                                           const double* __restrict__ vin) {
    double s = 0.0;
    int k = beg;
    for (; k + 4 <= end; k += 4) {
        int2 a0 = pair[k], a1 = pair[k + 1], a2 = pair[k + 2], a3 = pair[k + 3];
        double g0 = vin[a0.x], g1 = vin[a1.x], g2 = vin[a2.x], g3 = vin[a3.x];
        s += (double)__int_as_float(a0.y) * g0;
        s += (double)__int_as_float(a1.y) * g1;
        s += (double)__int_as_float(a2.y) * g2;
        s += (double)__int_as_float(a3.y) * g3;
    }
    for (; k < end; ++k) {
        int2 a = pair[k];
        s += (double)__int_as_float(a.y) * vin[a.x];
    }
    return s;
}

__device__ __forceinline__ double row_dot_d(const int2* __restrict__ pair,
                                            const float* __restrict__ dval, int beg, int end,
                                            const double* __restrict__ vin) {
    double s = 0.0;
    int k = beg;
    for (; k + 4 <= end; k += 4) {
        int c0 = pair[k].x, c1 = pair[k + 1].x, c2 = pair[k + 2].x, c3v = pair[k + 3].x;
        float d0 = dval[k], d1 = dval[k + 1], d2 = dval[k + 2], d3 = dval[k + 3];
        double g0 = vin[c0], g1 = vin[c1], g2 = vin[c2], g3 = vin[c3v];
        s += (double)d0 * g0;
        s += (double)d1 * g1;
        s += (double)d2 * g2;
        s += (double)d3 * g3;
    }
    for (; k < end; ++k)
        s += (double)dval[k] * vin[pair[k].x];
    return s;
}

// ---------------- setup: init + histogram + scan + fill ----------------
__global__ __launch_bounds__(TPB) void k_init(double* sc, const float* y, const float* s,
                                              const float* x, double* mask_d, double* xpim,
                                              double* xcg, double* red,
                                              int* nP, int* cntGn, int* cntAr) {
    long i = (long)blockIdx.x * TPB + threadIdx.x;
    if (i < NSLOT) sc[i] = 0.0;
    if (i < REDSZ) red[i] = 0.0;
    if (i < M_DIM) {
        double v = (double)y[i] - (double)s[i];
        mask_d[i] = v > 0.0 ? 1.0 : 0.0;
        xpim[N_DIM + i] = v > 0.0 ? v : 0.0;   // pi_m
        cntAr[i] = 0;
    }
    if (i < N_DIM) {
        xpim[i] = (double)x[i];
        nP[i] = 0; cntGn[i] = 0;
    }
    if (i < NM1) xcg[i] = 0.0;
}

__global__ __launch_bounds__(TPB) void k_hist(const int* Ar, const int* Ac, const int* Pr,
                                              int* nP, int* cntGn, int* cntAr) {
    long k = (long)blockIdx.x * TPB + threadIdx.x;
    if (k < NNZ_A) {
        atomicAdd(&cntGn[Ac[k]], 1);
        atomicAdd(&cntAr[Ar[k]], 1);
    }
    if (k < NNZ_P) atomicAdd(&nP[Pr[k]], 1);
}

// combine + even-pad both row-length arrays
__global__ __launch_bounds__(TPB) void k_comb(const int* nP, int* cntGn, int* cntAr) {
    int i = blockIdx.x * TPB + threadIdx.x;
    if (i < N_DIM) { int c = cntGn[i] + nP[i]; cntGn[i] = c + (c & 1); }
    if (i < M_DIM) { int c = cntAr[i]; cntAr[i] = c + (c & 1); }
}

__global__ __launch_bounds__(TPB) void k_scan1(const int* cnt, int len, int* exc, int* blksum) {
    __shared__ int sb[TPB];
    int i = blockIdx.x * TPB + threadIdx.x;
    int v = (i < len) ? cnt[i] : 0;
    sb[threadIdx.x] = v;
    __syncthreads();
    for (int sh = 1; sh < TPB; sh <<= 1) {
        int t = (threadIdx.x >= sh) ? sb[threadIdx.x - sh] : 0;
        __syncthreads();
        sb[threadIdx.x] += t;
        __syncthreads();
    }
    if (i < len) exc[i] = sb[threadIdx.x] - v;
    if (threadIdx.x == TPB - 1) blksum[blockIdx.x] = sb[TPB - 1];
}

__global__ __launch_bounds__(1024) void k_scan2(int* blksum, int nb, int* total_out) {
    __shared__ int sb[1024];
    int t = threadIdx.x;
    int v = (t < nb) ? blksum[t] : 0;
    sb[t] = v;
    __syncthreads();
    for (int sh = 1; sh < 1024; sh <<= 1) {
        int x = (t >= sh) ? sb[t - sh] : 0;
        __syncthreads();
        sb[t] += x;
        __syncthreads();
    }
    if (t < nb) blksum[t] = sb[t] - v;
    if (t == nb - 1) *total_out = sb[t];
}

__global__ __launch_bounds__(TPB) void k_scan3(int* exc, const int* blksum, int len, int* cur) {
    int i = blockIdx.x * TPB + threadIdx.x;
    if (i < len) {
        int v = exc[i] + blksum[blockIdx.x];
        exc[i] = v;
        cur[i] = v;
    }
}

// fills: P entries FIRST per G_n row (prefix nP[i]), then A^T entries; Ar separate
__global__ __launch_bounds__(TPB) void k_fillGnP(const int* Pr, const int* Pc, const float* Pv,
                                                 const float* dPv, int* curGn,
                                                 int2* pGn, float* dvalGn) {
    long k = (long)blockIdx.x * TPB + threadIdx.x;
    if (k < NNZ_P) {
        int pos = atomicAdd(&curGn[Pr[k]], 1);
        pGn[pos] = make_int2(Pc[k], __float_as_int(Pv[k]));
        dvalGn[pos] = dPv[k];
    }
}
__global__ __launch_bounds__(TPB) void k_fillGnA(const int* Ar, const int* Ac, const float* Av,
                                                 const float* dAv, int* curGn,
                                                 int2* pGn, float* dvalGn) {
    long k = (long)blockIdx.x * TPB + threadIdx.x;
    if (k < NNZ_A) {
        int pos = atomicAdd(&curGn[Ac[k]], 1);
        pGn[pos] = make_int2(N_DIM + Ar[k], __float_as_int(Av[k]));
        dvalGn[pos] = dAv[k];
    }
}
__global__ __launch_bounds__(TPB) void k_fillAr(const int* Ar, const int* Ac, const float* Av,
                                                const float* dAv, int* curAr,
                                                int2* pAr, float* dvalAr) {
    long k = (long)blockIdx.x * TPB + threadIdx.x;
    if (k < NNZ_A) {
        int pos = atomicAdd(&curAr[Ar[k]], 1);
        pAr[pos] = make_int2(Ac[k], __float_as_int(Av[k]));
        dvalAr[pos] = dAv[k];
    }
}

// zero the (at most one) pad slot per row; cur = cursor after fills = rptr[i]+realLen
__global__ __launch_bounds__(TPB) void k_pad(const int* cur, const int* rptr,
                                             int2* pair, float* dval, int nrows) {
    int i = blockIdx.x * TPB + threadIdx.x;
    if (i < nrows) {
        int c = cur[i], e = rptr[i + 1];
        if (c < e) { pair[c] = make_int2(0, 0); dval[c] = 0.0f; }
    }
}

// fused: Px, dpx, c3, dd_n (P entries are the nP-prefix of each G_n row; pads have dval=val=0)
__global__ __launch_bounds__(TPB) void k_setup_n(const int* __restrict__ rptrGn,
                                                 const int2* __restrict__ pGn,
                                                 const float* __restrict__ dvalGn,
                                                 const int* __restrict__ nP,
                                                 const double* __restrict__ xpim,
                                                 const float* __restrict__ q,
                                                 const float* __restrict__ dq,
                                                 double* Px, double* dpx, double* c3, double* dd) {
    int i = blockIdx.x * TPB + threadIdx.x;
    if (i >= N_DIM) return;
    int beg = rptrGn[i], end = rptrGn[i + 1];
    int np = nP[i];
    double px = 0.0, dpxv = 0.0, sa = 0.0;
    for (int k = beg; k < end; ++k) {
        int2 e = pGn[k];
        float dv = dvalGn[k];
        double g = xpim[e.x];
        if (k - beg < np) {
            px += (double)__int_as_float(e.y) * g;
            dpxv += (double)dv * g;
        } else {
            sa += (double)dv * g;
        }
    }
    Px[i] = px;
    dpx[i] = dpxv;
    c3[i] = (double)q[i] + 2.0 * px;
    dd[i] = dpxv + sa + (double)dq[i];
}

// fused: dd_m = -(dA x) + db
__global__ __launch_bounds__(TPB) void k_setup_m(const int* __restrict__ rptrAr,
                                                 const int2* __restrict__ pAr,
                                                 const float* __restrict__ dvalAr,
                                                 const double* __restrict__ xpim,
                                                 const float* __restrict__ db, double* dd) {
    int j = blockIdx.x * TPB + threadIdx.x;
    if (j >= M_DIM) return;
    double s = row_dot_d(pAr, dvalAr, rptrAr[j], rptrAr[j + 1], xpim);
    dd[N_DIM + j] = -s + (double)db[j];
}

// ---------------- dots & small elementwise ----------------
__global__ __launch_bounds__(TPB) void k_dot_fd(const float* a, const double* b, long len, double* dst) {
    long i = (long)blockIdx.x * TPB + threadIdx.x;
    double loc = 0.0;
    if (i < len) loc = (double)a[i] * b[i];
    blk_red_add(loc, dst);
}
__global__ __launch_bounds__(TPB) void k_dot_ff(const float* a, const float* b, long len, double* dst) {
    long i = (long)blockIdx.x * TPB + threadIdx.x;
    double loc = 0.0;
    if (i < len) loc = (double)a[i] * (double)b[i];
    blk_red_add(loc, dst);
}
__global__ __launch_bounds__(64) void k_dd_t(double* sc, double* dd) {
    if (threadIdx.x == 0) dd[NMSUM] = -sc[1] - sc[2] - sc[3];
}
// dd = -dd ; WC = [W_n ; -W_m]
__global__ __launch_bounds__(TPB) void k_negWC(double* dd, double* WC) {
    int i = blockIdx.x * TPB + threadIdx.x;
    if (i < NM1) {
        double nv = -dd[i];
        dd[i] = nv;
        if (i < N_DIM) WC[i] = nv;
        else if (i < NMSUM) WC[i] = -nv;
    }
}
__global__ __launch_bounds__(TPB) void k_rn(const int* __restrict__ rptrGn, const int2* __restrict__ pGn,
                                            const double* __restrict__ WC,
                                            const double* __restrict__ c3,
                                            const double* __restrict__ dd, double* r) {
    int i = blockIdx.x * TPB + threadIdx.x;
    if (i >= N_DIM) return;
    double s = row_dot8(pGn, rptrGn[i], rptrGn[i + 1], WC);   // P wn - A^T wm
    r[i] = s - c3[i] * dd[NMSUM];
}
__global__ __launch_bounds__(TPB) void k_rm(const int* __restrict__ rptrAr, const int2* __restrict__ pAr,
                                            const double* __restrict__ WC,
                                            const double* __restrict__ mask_d,
                                            const float* __restrict__ b,
                                            const double* __restrict__ dd, double* r) {
    int j = blockIdx.x * TPB + threadIdx.x;
    if (j >= M_DIM) return;
    double s = row_dot8(pAr, rptrAr[j], rptrAr[j + 1], WC);   // A wn
    double wt = dd[NMSUM];
    double tmv = s - (double)b[j] * wt;
    double wm = dd[N_DIM + j];
    r[N_DIM + j] = mask_d[j] * (tmv - wm) + wm;
}
__global__ __launch_bounds__(64) void k_ft_t(const double* e1, const double* e2, const double* xtpx,
                                             const double* W, double* U) {
    if (threadIdx.x == 0) U[NMSUM] = (*e1) + (*e2) + (*xtpx) * W[NMSUM];
}
__global__ __launch_bounds__(TPB) void k_cginit(const double* r, double* p, double* red) {
    int i = blockIdx.x * TPB + threadIdx.x;
    double loc = 0.0;
    if (i < NM1) { double v = r[i]; p[i] = v; loc = v * v; }
    double* gslot = red + 20 * 5 * 64;
    blk_red_add(loc, &gslot[blockIdx.x & 63]);
}

// ---------------- fused per-iteration kernels (4 launches/iter) ----------------
// K1: p-update + pum=[p_n; um] + d1,d2 (slot-split)
__global__ __launch_bounds__(TPB) void k_iterA(const double* r, double* p,
                                               const double* mask_d, const double* c3,
                                               const float* b, double* pum,
                                               double* red, int it) {
    double* ds = red + (long)it * 5 * 64;
    double* gslot = red + 20 * 5 * 64;
    double beta = 0.0;
    if (it > 0) {
        double gn = blk_sum64w(gslot + (long)it * 64);
        double gp = blk_sum64w(gslot + (long)(it - 1) * 64);
        beta = gn / gp;
    }
    long i = (long)blockIdx.x * TPB + threadIdx.x;
    int slot = blockIdx.x & 63;
    double l1 = 0.0, l2 = 0.0;
    if (i < NM1) {
        double pn;
        if (it > 0) {
            pn = r[i] + beta * p[i];
            p[i] = pn;
        } else {
            pn = p[i];
        }
        if (i < N_DIM) {
            l1 = c3[i] * pn;
            pum[i] = pn;
        } else if (i < NMSUM) {
            int j = (int)(i - N_DIM);
            double u = mask_d[j] * pn;
            pum[i] = u;
            l2 = (double)b[j] * u;
        }
    }
    blk_red_add(l1, ds + 0 * 64 + slot);   // d1
    blk_red_add(l2, ds + 1 * 64 + slot);   // d2
}

// K2: Fmv — int4 row dots over pum; Fpc=[v_n; -v_m]; last (idle) block: F_tau -> sc[16+it]
__global__ __launch_bounds__(TPB) void k_fmv(const int* __restrict__ rptrGn, const int2* __restrict__ pGn,
                                             const int* __restrict__ rptrAr, const int2* __restrict__ pAr,
                                             const float* __restrict__ q, const float* __restrict__ b,
                                             const double* __restrict__ p, const double* __restrict__ pum,
                                             double* __restrict__ Fpc, double* sc, double* red, int it) {
    const int4* pGn4 = (const int4*)pGn;
    const int4* pAr4 = (const int4*)pAr;
    double* ds = red + (long)it * 5 * 64;
    long i = (long)blockIdx.x * TPB + threadIdx.x;
    int slot = blockIdx.x & 63;
    double ut = p[NMSUM];
    double l1 = 0.0, l2 = 0.0;
    if (i < N_DIM) {
        double s = row_dotx4(pGn4, rptrGn[i] >> 1, rptrGn[i + 1] >> 1, pum);  // P p + A^T um
        double r1 = s + (double)q[i] * ut;
        double v = (r1 - p[i]) + p[i];
        Fpc[i] = v;
        l1 = (double)q[i] * v;
    } else if (i < NMSUM) {
        int j = (int)(i - N_DIM);
        double s = row_dotx4(pAr4, rptrAr[j] >> 1, rptrAr[j + 1] >> 1, pum);  // A p_n
        double r2 = -s + (double)b[j] * ut;
        double v = (r2 - pum[i]) + p[i];
        Fpc[i] = -v;
        l2 = (double)b[j] * v;
    }
    blk_red_add(l1, ds + 2 * 64 + slot);   // e1
    blk_red_add(l2, ds + 3 * 64 + slot);   // e2
    if (blockIdx.x == gridDim.x - 1) {     // idle block (covers i >= 300032)
        double d1 = blk_sum64w(ds + 0 * 64);
        double d2 = blk_sum64w(ds + 1 * 64);
        if (threadIdx.x == 0) {
            double r3 = -d1 - d2 + sc[0] * ut;
            sc[16 + it] = (r3 - ut) + ut;   // F_tau
        }
    }
}

// K3: FTmv — int4 row dots over Fpc; Ap + pq; last block: tau row
__global__ __launch_bounds__(TPB) void k_ftmv(const int* __restrict__ rptrGn, const int2* __restrict__ pGn,
                                              const int* __restrict__ rptrAr, const int2* __restrict__ pAr,
                                              const float* __restrict__ b, const double* __restrict__ mask_d,
                                              const double* __restrict__ c3,
                                              const double* __restrict__ Fpc, const double* __restrict__ p,
                                              double* __restrict__ Ap, double* sc, double* red, int it) {
    const int4* pGn4 = (const int4*)pGn;
    const int4* pAr4 = (const int4*)pAr;
    double* ds = red + (long)it * 5 * 64;
    long i = (long)blockIdx.x * TPB + threadIdx.x;
    int slot = blockIdx.x & 63;
    double wt = sc[16 + it];
    double l = 0.0;
    if (i < N_DIM) {
        double s = row_dotx4(pGn4, rptrGn[i] >> 1, rptrGn[i + 1] >> 1, Fpc);  // P Fp_n - A^T Fp_m
        double v = s - c3[i] * wt;
        Ap[i] = v;
        l = p[i] * v;
    } else if (i < NMSUM) {
        int j = (int)(i - N_DIM);
        double s = row_dotx4(pAr4, rptrAr[j] >> 1, rptrAr[j + 1] >> 1, Fpc);  // A Fp_n
        double tmv = s - (double)b[j] * wt;
        double wm = -Fpc[i];
        double v = mask_d[j] * (tmv - wm) + wm;
        Ap[i] = v;
        l = p[i] * v;
    }
    blk_red_add(l, ds + 4 * 64 + slot);    // pq (row part)
    if (blockIdx.x == gridDim.x - 1) {
        double e1 = blk_sum64w(ds + 2 * 64);
        double e2 = blk_sum64w(ds + 3 * 64);
        if (threadIdx.x == 0) {
            double tt = e1 + e2 + sc[0] * wt;
            Ap[NMSUM] = tt;
            atomicAdd(ds + 4 * 64 + slot, p[NMSUM] * tt);   // tau term of pq
        }
    }
}

// K4: alpha from slots, x/r update + gam[it+1] slots
__global__ __launch_bounds__(TPB) void k_upd(const double* p, const double* Ap,
                                             double* xcg, double* r, double* red, int it) {
    double* ds = red + (long)it * 5 * 64;
    double* gslot = red + 20 * 5 * 64;
    double gcur = blk_sum64w(gslot + (long)it * 64);
    double pq = blk_sum64w(ds + 4 * 64);
    double alpha = gcur / pq;
    long i = (long)blockIdx.x * TPB + threadIdx.x;
    int slot = blockIdx.x & 63;
    double l = 0.0;
    if (i < NM1) {
        xcg[i] += alpha * p[i];
        double rn = r[i] - alpha * Ap[i];
        r[i] = rn;
        l = rn * rn;
    }
    blk_red_add(l, gslot + (long)(it + 1) * 64 + slot);
}

__global__ __launch_bounds__(TPB) void k_final(const double* xcg, const double* mask_d,
                                               const float* x, const float* y, const float* s,
                                               float* out) {
    int i = blockIdx.x * TPB + threadIdx.x;
    double dzt = xcg[NMSUM];
    if (i < N_DIM) {
        out[i] = (float)(xcg[i] - (double)x[i] * dzt);
    } else if (i < NMSUM) {
        int j = i - N_DIM;
        double dzm = xcg[N_DIM + j];
        double t = mask_d[j] * dzm;
        out[N_DIM + j] = (float)(t - (double)y[j] * dzt);
        out[N_DIM + M_DIM + j] = (float)(t - dzm - (double)s[j] * dzt);
    }
}

extern "C" void kernel_launch(void* const* d_in, const int* in_sizes, int n_in,
                              void* d_out, int out_size, void* d_ws, size_t ws_size,
                              hipStream_t stream) {
    const int*   Pr  = (const int*)d_in[0];
    const int*   Pc  = (const int*)d_in[1];
    const float* Pv  = (const float*)d_in[2];
    const int*   Ar  = (const int*)d_in[3];
    const int*   Ac  = (const int*)d_in[4];
    const float* Av  = (const float*)d_in[5];
    const float* q   = (const float*)d_in[6];
    const float* b   = (const float*)d_in[7];
    const float* x   = (const float*)d_in[8];
    const float* yv  = (const float*)d_in[9];
    const float* sv  = (const float*)d_in[10];
    const float* dPv = (const float*)d_in[11];
    const float* dAv = (const float*)d_in[12];
    const float* dq  = (const float*)d_in[13];
    const float* db  = (const float*)d_in[14];
    float* out = (float*)d_out;

    char* wp = (char*)d_ws;
    auto alloc = [&](size_t bytes) { char* r0 = wp; wp += (bytes + 255) & ~255ull; return r0; };

    double* sc     = (double*)alloc(NSLOT * 8);
    double* red    = (double*)alloc((size_t)REDSZ * 8);
    double* mask_d = (double*)alloc((size_t)M_DIM * 8);
    double* xpim   = (double*)alloc((size_t)NMSUM * 8);   // [x ; pi_m]
    double* Px     = (double*)alloc((size_t)N_DIM * 8);
    double* dpx    = (double*)alloc((size_t)N_DIM * 8);
    double* c3     = (double*)alloc((size_t)N_DIM * 8);
    double* dd     = (double*)alloc((size_t)NM1 * 8);
    double* r      = (double*)alloc((size_t)NM1 * 8);
    double* p      = (double*)alloc((size_t)NM1 * 8);
    double* xcg    = (double*)alloc((size_t)NM1 * 8);
    double* Ap     = (double*)alloc((size_t)NM1 * 8);
    double* pum    = (double*)alloc((size_t)NMSUM * 8);   // [p_n ; um]
    double* Fpc    = (double*)alloc((size_t)NMSUM * 8);   // [Fp_n ; -Fp_m]
    double* WC     = (double*)alloc((size_t)NMSUM * 8);   // [W_n ; -W_m]
    int2*  pGn    = (int2*)alloc(((size_t)NNZ_GN + N_DIM) * 8);
    int2*  pAr    = (int2*)alloc(((size_t)NNZ_A + M_DIM) * 8);
    float* dvalGn = (float*)alloc(((size_t)NNZ_GN + N_DIM) * 4);
    float* dvalAr = (float*)alloc(((size_t)NNZ_A + M_DIM) * 4);
    int*   rptrGn = (int*)alloc((size_t)(N_DIM + 1) * 4);
    int*   rptrAr = (int*)alloc((size_t)(M_DIM + 1) * 4);
    int*   nP     = (int*)alloc((size_t)N_DIM * 4);
    int*   cntGn  = (int*)alloc((size_t)N_DIM * 4);   // becomes cursor after scan
    int*   cntAr  = (int*)alloc((size_t)M_DIM * 4);   // becomes cursor after scan
    int*   blks   = (int*)alloc(1024 * 4);

    double* xtpx = sc + 0;

    auto g = [](long n) { return dim3((unsigned)((n + TPB - 1) / TPB)); };

    // ---- CSR build (rows padded to even length) ----
    hipLaunchKernelGGL(k_init, g(NM1), dim3(TPB), 0, stream, sc, yv, sv, x, mask_d, xpim, xcg, red,
                       nP, cntGn, cntAr);
    hipLaunchKernelGGL(k_hist, g(NNZ_A), dim3(TPB), 0, stream, Ar, Ac, Pr, nP, cntGn, cntAr);
    hipLaunchKernelGGL(k_comb, g(M_DIM), dim3(TPB), 0, stream, nP, cntGn, cntAr);

    auto scan = [&](int* cnt, int len, int* rptr) {
        int nb = (len + TPB - 1) / TPB;
        hipLaunchKernelGGL(k_scan1, dim3((unsigned)nb), dim3(TPB), 0, stream, cnt, len, rptr, blks);
        hipLaunchKernelGGL(k_scan2, dim3(1), dim3(1024), 0, stream, blks, nb, rptr + len);
        hipLaunchKernelGGL(k_scan3, dim3((unsigned)nb), dim3(TPB), 0, stream, rptr, blks, len, cnt);
    };
    scan(cntGn, N_DIM, rptrGn);   // cntGn becomes cursor
    scan(cntAr, M_DIM, rptrAr);   // cntAr becomes cursor

    // P entries first (prefix), then A^T entries; then zero pad slots
    hipLaunchKernelGGL(k_fillGnP, g(NNZ_P), dim3(TPB), 0, stream, Pr, Pc, Pv, dPv, cntGn, pGn, dvalGn);
    hipLaunchKernelGGL(k_fillGnA, g(NNZ_A), dim3(TPB), 0, stream, Ar, Ac, Av, dAv, cntGn, pGn, dvalGn);
    hipLaunchKernelGGL(k_fillAr,  g(NNZ_A), dim3(TPB), 0, stream, Ar, Ac, Av, dAv, cntAr, pAr, dvalAr);
    hipLaunchKernelGGL(k_pad, g(N_DIM), dim3(TPB), 0, stream, cntGn, rptrGn, pGn, dvalGn, N_DIM);
    hipLaunchKernelGGL(k_pad, g(M_DIM), dim3(TPB), 0, stream, cntAr, rptrAr, pAr, dvalAr, M_DIM);

    // ---- setup math ----
    hipLaunchKernelGGL(k_setup_n, g(N_DIM), dim3(TPB), 0, stream, rptrGn, pGn, dvalGn, nP,
                       xpim, q, dq, Px, dpx, c3, dd);
    hipLaunchKernelGGL(k_setup_m, g(M_DIM), dim3(TPB), 0, stream, rptrAr, pAr, dvalAr, xpim, db, dd);
    hipLaunchKernelGGL(k_dot_fd, g(N_DIM), dim3(TPB), 0, stream, x, Px, (long)N_DIM, xtpx);
    hipLaunchKernelGGL(k_dot_ff, g(N_DIM), dim3(TPB), 0, stream, dq, x, (long)N_DIM, sc + 1);
    hipLaunchKernelGGL(k_dot_fd, g(M_DIM), dim3(TPB), 0, stream, db, xpim + N_DIM, (long)M_DIM, sc + 2);
    hipLaunchKernelGGL(k_dot_fd, g(N_DIM), dim3(TPB), 0, stream, x, dpx, (long)N_DIM, sc + 3);
    hipLaunchKernelGGL(k_dd_t, dim3(1), dim3(64), 0, stream, sc, dd);
    hipLaunchKernelGGL(k_negWC, g(NM1), dim3(TPB), 0, stream, dd, WC);
    hipLaunchKernelGGL(k_rn, g(N_DIM), dim3(TPB), 0, stream, rptrGn, pGn, WC, c3, dd, r);
    hipLaunchKernelGGL(k_rm, g(M_DIM), dim3(TPB), 0, stream, rptrAr, pAr, WC, mask_d, b, dd, r);
    hipLaunchKernelGGL(k_dot_fd, g(N_DIM), dim3(TPB), 0, stream, q, dd, (long)N_DIM, sc + 8);
    hipLaunchKernelGGL(k_dot_fd, g(M_DIM), dim3(TPB), 0, stream, b, dd + N_DIM, (long)M_DIM, sc + 9);
    hipLaunchKernelGGL(k_ft_t, dim3(1), dim3(64), 0, stream, sc + 8, sc + 9, xtpx, dd, r);
    hipLaunchKernelGGL(k_cginit, g(NM1), dim3(TPB), 0, stream, r, p, red);

    // ---- 20 CG iterations, 4 fused launches each ----
    for (int it = 0; it < CG_ITERS; ++it) {
        hipLaunchKernelGGL(k_iterA, g(NM1), dim3(TPB), 0, stream, r, p, mask_d, c3, b, pum, red, it);
        hipLaunchKernelGGL(k_fmv,   g(NM1), dim3(TPB), 0, stream, rptrGn, pGn, rptrAr, pAr,
                           q, b, p, pum, Fpc, sc, red, it);
        hipLaunchKernelGGL(k_ftmv,  g(NM1), dim3(TPB), 0, stream, rptrGn, pGn, rptrAr, pAr,
                           b, mask_d, c3, Fpc, p, Ap, sc, red, it);
        hipLaunchKernelGGL(k_upd,   g(NM1), dim3(TPB), 0, stream, p, Ap, xcg, r, red, it);
    }

    hipLaunchKernelGGL(k_final, g(NMSUM), dim3(TPB), 0, stream, xcg, mask_d, x, yv, sv, out);
}

// Round 9
// 2342.924 us; speedup vs baseline: 5.1281x; 1.0781x over previous
//
#include <hip/hip_runtime.h>

#define N_DIM 100000
#define M_DIM 200000
#define NNZ_A 2000000
#define NNZ_P 500000
#define NNZ_GN (NNZ_A + NNZ_P)
#define NMSUM 300000
#define NM1   300001
#define CG_ITERS 20
#define TPB 256
#define NSLOT 512
#define GOFF (20 * 5 * 64)            // gamma slots at red+GOFF, [21][64]
#define SETOFF (GOFF + 21 * 64)       // setup slots: xtpx,s1,s2,s3,s8,s9 each [64]
#define REDSZ (SETOFF + 6 * 64)

// sc[0]=xTPx (scalar, written by negWC), sc[16+it]=F_tau per iter

__device__ __forceinline__ void blk_red_add(double v, double* dst) {
    __shared__ double sb[TPB];
    int tid = threadIdx.x;
    __syncthreads();
    sb[tid] = v;
    __syncthreads();
    for (int sh = TPB / 2; sh > 0; sh >>= 1) {
        if (tid < sh) sb[tid] += sb[tid + sh];
        __syncthreads();
    }
    if (tid == 0) atomicAdd(dst, sb[0]);
}

// sum 64 slots, broadcast to all threads of the block
__device__ __forceinline__ double blk_sum64w(const double* src) {
    __shared__ double bsh;
    int t = threadIdx.x;
    if (t < 64) {
        double v = src[t];
        v += __shfl_xor(v, 32); v += __shfl_xor(v, 16); v += __shfl_xor(v, 8);
        v += __shfl_xor(v, 4);  v += __shfl_xor(v, 2);  v += __shfl_xor(v, 1);
        if (t == 0) bsh = v;
    }
    __syncthreads();
    double r = bsh;
    __syncthreads();
    return r;
}

// full-row 2-pair int4 dot (rows padded even; pad = {0,0.0f} -> +0.0)
__device__ __forceinline__ double row_dotx4(const int4* __restrict__ pp, int b2, int e2,
                                            const double* __restrict__ vin) {
    double s = 0.0;
    int k = b2;
    for (; k + 4 <= e2; k += 4) {
        int4 a = pp[k], b = pp[k + 1], c = pp[k + 2], d = pp[k + 3];
        double g0 = vin[a.x], g1 = vin[a.z], g2 = vin[b.x], g3 = vin[b.z];
        double g4 = vin[c.x], g5 = vin[c.z], g6 = vin[d.x], g7 = vin[d.z];
        s += (double)__int_as_float(a.y) * g0;
        s += (double)__int_as_float(a.w) * g1;
        s += (double)__int_as_float(b.y) * g2;
        s += (double)__int_as_float(b.w) * g3;
        s += (double)__int_as_float(c.y) * g4;
        s += (double)__int_as_float(c.w) * g5;
        s += (double)__int_as_float(d.y) * g6;
        s += (double)__int_as_float(d.w) * g7;
    }
    for (; k < e2; ++k) {
        int4 a = pp[k];
        s += (double)__int_as_float(a.y) * vin[a.x];
        s += (double)__int_as_float(a.w) * vin[a.z];
    }
    return s;
}

// 2-thread-per-row: contiguous halves of the int4 slots, one shfl to combine.
// Both lanes of the pair return the full row sum.
__device__ __forceinline__ double row_dotx4_half(const int4* __restrict__ pp, int b2, int e2,
                                                 const double* __restrict__ vin, int half) {
    int len = e2 - b2;
    int h1 = (len + 1) >> 1;
    int kb = b2 + (half ? h1 : 0);
    int ke = half ? e2 : (b2 + h1);
    double s = 0.0;
    int k = kb;
    for (; k + 4 <= ke; k += 4) {
        int4 a = pp[k], b = pp[k + 1], c = pp[k + 2], d = pp[k + 3];
        double g0 = vin[a.x], g1 = vin[a.z], g2 = vin[b.x], g3 = vin[b.z];
        double g4 = vin[c.x], g5 = vin[c.z], g6 = vin[d.x], g7 = vin[d.z];
        s += (double)__int_as_float(a.y) * g0;
        s += (double)__int_as_float(a.w) * g1;
        s += (double)__int_as_float(b.y) * g2;
        s += (double)__int_as_float(b.w) * g3;
        s += (double)__int_as_float(c.y) * g4;
        s += (double)__int_as_float(c.w) * g5;
        s += (double)__int_as_float(d.y) * g6;
        s += (double)__int_as_float(d.w) * g7;
    }
    for (; k + 2 <= ke; k += 2) {
        int4 a = pp[k], b = pp[k + 1];
        double g0 = vin[a.x], g1 = vin[a.z], g2 = vin[b.x], g3 = vin[b.z];
        s += (double)__int_as_float(a.y) * g0;
        s += (double)__int_as_float(a.w) * g1;
        s += (double)__int_as_float(b.y) * g2;
        s += (double)__int_as_float(b.w) * g3;
    }
    if (k < ke) {
        int4 a = pp[k];
        s += (double)__int_as_float(a.y) * vin[a.x];
        s += (double)__int_as_float(a.w) * vin[a.z];
    }
    s += __shfl_xor(s, 1);
    return s;
}

__device__ __forceinline__ double row_dot_d(const int2* __restrict__ pair,
                                            const float* __restrict__ dval, int beg, int end,
                                            const double* __restrict__ vin) {
    double s = 0.0;
    int k = beg;
    for (; k + 4 <= end; k += 4) {
        int c0 = pair[k].x, c1 = pair[k + 1].x, c2 = pair[k + 2].x, c3v = pair[k + 3].x;
        float d0 = dval[k], d1 = dval[k + 1], d2 = dval[k + 2], d3 = dval[k + 3];
        double g0 = vin[c0], g1 = vin[c1], g2 = vin[c2], g3 = vin[c3v];
        s += (double)d0 * g0;
        s += (double)d1 * g1;
        s += (double)d2 * g2;
        s += (double)d3 * g3;
    }
    for (; k < end; ++k)
        s += (double)dval[k] * vin[pair[k].x];
    return s;
}

// ---------------- setup: init + histogram + scan + fill ----------------
__global__ __launch_bounds__(TPB) void k_init(double* sc, const float* y, const float* s,
                                              const float* x, double* mask_d, double* xpim,
                                              double* xcg, double* red,
                                              int* nP, int* cntGn, int* cntAr) {
    long i = (long)blockIdx.x * TPB + threadIdx.x;
    if (i < NSLOT) sc[i] = 0.0;
    if (i < REDSZ) red[i] = 0.0;
    if (i < M_DIM) {
        double v = (double)y[i] - (double)s[i];
        mask_d[i] = v > 0.0 ? 1.0 : 0.0;
        xpim[N_DIM + i] = v > 0.0 ? v : 0.0;   // pi_m
        cntAr[i] = 0;
    }
    if (i < N_DIM) {
        xpim[i] = (double)x[i];
        nP[i] = 0; cntGn[i] = 0;
    }
    if (i < NM1) xcg[i] = 0.0;
}

__global__ __launch_bounds__(TPB) void k_hist(const int* Ar, const int* Ac, const int* Pr,
                                              int* nP, int* cntGn, int* cntAr) {
    long k = (long)blockIdx.x * TPB + threadIdx.x;
    if (k < NNZ_A) {
        atomicAdd(&cntGn[Ac[k]], 1);
        atomicAdd(&cntAr[Ar[k]], 1);
    }
    if (k < NNZ_P) atomicAdd(&nP[Pr[k]], 1);
}

// combine + even-pad both row-length arrays
__global__ __launch_bounds__(TPB) void k_comb(const int* nP, int* cntGn, int* cntAr) {
    int i = blockIdx.x * TPB + threadIdx.x;
    if (i < N_DIM) { int c = cntGn[i] + nP[i]; cntGn[i] = c + (c & 1); }
    if (i < M_DIM) { int c = cntAr[i]; cntAr[i] = c + (c & 1); }
}

__global__ __launch_bounds__(TPB) void k_scan1(const int* cnt, int len, int* exc, int* blksum) {
    __shared__ int sb[TPB];
    int i = blockIdx.x * TPB + threadIdx.x;
    int v = (i < len) ? cnt[i] : 0;
    sb[threadIdx.x] = v;
    __syncthreads();
    for (int sh = 1; sh < TPB; sh <<= 1) {
        int t = (threadIdx.x >= sh) ? sb[threadIdx.x - sh] : 0;
        __syncthreads();
        sb[threadIdx.x] += t;
        __syncthreads();
    }
    if (i < len) exc[i] = sb[threadIdx.x] - v;
    if (threadIdx.x == TPB - 1) blksum[blockIdx.x] = sb[TPB - 1];
}

__global__ __launch_bounds__(1024) void k_scan2(int* blksum, int nb, int* total_out) {
    __shared__ int sb[1024];
    int t = threadIdx.x;
    int v = (t < nb) ? blksum[t] : 0;
    sb[t] = v;
    __syncthreads();
    for (int sh = 1; sh < 1024; sh <<= 1) {
        int x = (t >= sh) ? sb[t - sh] : 0;
        __syncthreads();
        sb[t] += x;
        __syncthreads();
    }
    if (t < nb) blksum[t] = sb[t] - v;
    if (t == nb - 1) *total_out = sb[t];
}

__global__ __launch_bounds__(TPB) void k_scan3(int* exc, const int* blksum, int len, int* cur) {
    int i = blockIdx.x * TPB + threadIdx.x;
    if (i < len) {
        int v = exc[i] + blksum[blockIdx.x];
        exc[i] = v;
        cur[i] = v;
    }
}

// fills: P entries FIRST per G_n row (prefix nP[i]), then A^T entries; Ar separate
__global__ __launch_bounds__(TPB) void k_fillGnP(const int* Pr, const int* Pc, const float* Pv,
                                                 const float* dPv, int* curGn,
                                                 int2* pGn, float* dvalGn) {
    long k = (long)blockIdx.x * TPB + threadIdx.x;
    if (k < NNZ_P) {
        int pos = atomicAdd(&curGn[Pr[k]], 1);
        pGn[pos] = make_int2(Pc[k], __float_as_int(Pv[k]));
        dvalGn[pos] = dPv[k];
    }
}
__global__ __launch_bounds__(TPB) void k_fillGnA(const int* Ar, const int* Ac, const float* Av,
                                                 const float* dAv, int* curGn,
                                                 int2* pGn, float* dvalGn) {
    long k = (long)blockIdx.x * TPB + threadIdx.x;
    if (k < NNZ_A) {
        int pos = atomicAdd(&curGn[Ac[k]], 1);
        pGn[pos] = make_int2(N_DIM + Ar[k], __float_as_int(Av[k]));
        dvalGn[pos] = dAv[k];
    }
}
__global__ __launch_bounds__(TPB) void k_fillAr(const int* Ar, const int* Ac, const float* Av,
                                                const float* dAv, int* curAr,
                                                int2* pAr, float* dvalAr) {
    long k = (long)blockIdx.x * TPB + threadIdx.x;
    if (k < NNZ_A) {
        int pos = atomicAdd(&curAr[Ar[k]], 1);
        pAr[pos] = make_int2(Ac[k], __float_as_int(Av[k]));
        dvalAr[pos] = dAv[k];
    }
}

// zero the (at most one) pad slot per row for both matrices
__global__ __launch_bounds__(TPB) void k_pad(const int* curGn, const int* rptrGn,
                                             int2* pGn, float* dvalGn,
                                             const int* curAr, const int* rptrAr,
                                             int2* pAr, float* dvalAr) {
    int i = blockIdx.x * TPB + threadIdx.x;
    if (i < N_DIM) {
        int c = curGn[i], e = rptrGn[i + 1];
        if (c < e) { pGn[c] = make_int2(0, 0); dvalGn[c] = 0.0f; }
    }
    if (i < M_DIM) {
        int c = curAr[i], e = rptrAr[i + 1];
        if (c < e) { pAr[c] = make_int2(0, 0); dvalAr[c] = 0.0f; }
    }
}

// fused: c3, dd_n + slot-dots {xtpx, dq.x, x.dpx}
__global__ __launch_bounds__(TPB) void k_setup_n(const int* __restrict__ rptrGn,
                                                 const int2* __restrict__ pGn,
                                                 const float* __restrict__ dvalGn,
                                                 const int* __restrict__ nP,
                                                 const double* __restrict__ xpim,
                                                 const float* __restrict__ q,
                                                 const float* __restrict__ dq,
                                                 double* c3, double* dd, double* red) {
    int i = blockIdx.x * TPB + threadIdx.x;
    int slot = blockIdx.x & 63;
    double* S = red + SETOFF;
    double lx = 0.0, l1 = 0.0, l3 = 0.0;
    if (i < N_DIM) {
        int beg = rptrGn[i], end = rptrGn[i + 1];
        int np = nP[i];
        double px = 0.0, dpxv = 0.0, sa = 0.0;
        for (int k = beg; k < end; ++k) {
            int2 e = pGn[k];
            float dv = dvalGn[k];
            double g = xpim[e.x];
            if (k - beg < np) {
                px += (double)__int_as_float(e.y) * g;
                dpxv += (double)dv * g;
            } else {
                sa += (double)dv * g;
            }
        }
        c3[i] = (double)q[i] + 2.0 * px;
        dd[i] = dpxv + sa + (double)dq[i];
        double xi = xpim[i];
        lx = xi * px;
        l1 = (double)dq[i] * xi;
        l3 = xi * dpxv;
    }
    blk_red_add(lx, S + 0 * 64 + slot);   // xTPx
    blk_red_add(l1, S + 1 * 64 + slot);   // dq.x
    blk_red_add(l3, S + 3 * 64 + slot);   // x.dpx
}

// fused: dd_m = -(dA x) + db  + slot-dot {db.pim}
__global__ __launch_bounds__(TPB) void k_setup_m(const int* __restrict__ rptrAr,
                                                 const int2* __restrict__ pAr,
                                                 const float* __restrict__ dvalAr,
                                                 const double* __restrict__ xpim,
                                                 const float* __restrict__ db, double* dd,
                                                 double* red) {
    int j = blockIdx.x * TPB + threadIdx.x;
    int slot = blockIdx.x & 63;
    double* S = red + SETOFF;
    double l2 = 0.0;
    if (j < M_DIM) {
        double s = row_dot_d(pAr, dvalAr, rptrAr[j], rptrAr[j + 1], xpim);
        dd[N_DIM + j] = -s + (double)db[j];
        l2 = (double)db[j] * xpim[N_DIM + j];
    }
    blk_red_add(l2, S + 2 * 64 + slot);   // db.pim
}

// dd = -dd ; WC = [W_n ; -W_m]; tau thread computes dd[NMSUM] & sc[0]; slot-dots {q.W_n, b.W_m}
__global__ __launch_bounds__(TPB) void k_negWC(double* dd, double* WC,
                                               const float* q, const float* b,
                                               double* red, double* sc) {
    long i = (long)blockIdx.x * TPB + threadIdx.x;
    int slot = blockIdx.x & 63;
    double* S = red + SETOFF;
    double l8 = 0.0, l9 = 0.0;
    if (i == NMSUM) {
        double xt = 0.0, s1 = 0.0, s2 = 0.0, s3 = 0.0;
        for (int k = 0; k < 64; ++k) {
            xt += S[k]; s1 += S[64 + k]; s2 += S[128 + k]; s3 += S[192 + k];
        }
        sc[0] = xt;
        dd[NMSUM] = s1 + s2 + s3;   // = -(-s1-s2-s3)
    } else if (i < NM1) {
        double nv = -dd[i];
        dd[i] = nv;
        if (i < N_DIM) {
            WC[i] = nv;
            l8 = (double)q[i] * nv;
        } else {
            WC[i] = -nv;
            l9 = (double)b[i - N_DIM] * nv;
        }
    }
    blk_red_add(l8, S + 4 * 64 + slot);   // q.W_n
    blk_red_add(l9, S + 5 * 64 + slot);   // b.W_m
}

// merged r_n, r_m, r_tau + cginit (p=r, gamma0 slots)
__global__ __launch_bounds__(TPB) void k_r(const int* __restrict__ rptrGn, const int2* __restrict__ pGn,
                                           const int* __restrict__ rptrAr, const int2* __restrict__ pAr,
                                           const double* __restrict__ WC, const double* __restrict__ c3,
                                           const double* __restrict__ mask_d, const float* __restrict__ b,
                                           const double* __restrict__ dd, double* r, double* p,
                                           double* red, const double* sc) {
    const int4* pGn4 = (const int4*)pGn;
    const int4* pAr4 = (const int4*)pAr;
    long i = (long)blockIdx.x * TPB + threadIdx.x;
    int slot = blockIdx.x & 63;
    double* S = red + SETOFF;
    double* gslot = red + GOFF;
    double rv = 0.0;
    bool wr = false;
    if (i < N_DIM) {
        double s = row_dotx4(pGn4, rptrGn[i] >> 1, rptrGn[i + 1] >> 1, WC);   // P wn - A^T wm
        rv = s - c3[i] * dd[NMSUM];
        wr = true;
    } else if (i < NMSUM) {
        int j = (int)(i - N_DIM);
        double s = row_dotx4(pAr4, rptrAr[j] >> 1, rptrAr[j + 1] >> 1, WC);   // A wn
        double wt = dd[NMSUM];
        double tmv = s - (double)b[j] * wt;
        double wm = dd[i];
        rv = mask_d[j] * (tmv - wm) + wm;
        wr = true;
    } else if (i == NMSUM) {
        double e1 = 0.0, e2 = 0.0;
        for (int k = 0; k < 64; ++k) { e1 += S[4 * 64 + k]; e2 += S[5 * 64 + k]; }
        rv = e1 + e2 + sc[0] * dd[NMSUM];
        wr = true;
    }
    double l = 0.0;
    if (wr) { r[i] = rv; p[i] = rv; l = rv * rv; }
    blk_red_add(l, gslot + slot);
}

// ---------------- fused per-iteration kernels (4 launches/iter) ----------------
// K1: p-update + pum=[p_n; um] + d1,d2 (slot-split)
__global__ __launch_bounds__(TPB) void k_iterA(const double* r, double* p,
                                               const double* mask_d, const double* c3,
                                               const float* b, double* pum,
                                               double* red, int it) {
    double* ds = red + (long)it * 5 * 64;
    double* gslot = red + GOFF;
    double beta = 0.0;
    if (it > 0) {
        double gn = blk_sum64w(gslot + (long)it * 64);
        double gp = blk_sum64w(gslot + (long)(it - 1) * 64);
        beta = gn / gp;
    }
    long i = (long)blockIdx.x * TPB + threadIdx.x;
    int slot = blockIdx.x & 63;
    double l1 = 0.0, l2 = 0.0;
    if (i < NM1) {
        double pn;
        if (it > 0) {
            pn = r[i] + beta * p[i];
            p[i] = pn;
        } else {
            pn = p[i];
        }
        if (i < N_DIM) {
            l1 = c3[i] * pn;
            pum[i] = pn;
        } else if (i < NMSUM) {
            int j = (int)(i - N_DIM);
            double u = mask_d[j] * pn;
            pum[i] = u;
            l2 = (double)b[j] * u;
        }
    }
    blk_red_add(l1, ds + 0 * 64 + slot);   // d1
    blk_red_add(l2, ds + 1 * 64 + slot);   // d2
}

// K2: Fmv — 2-thread-per-row int4 dots over pum; Fpc=[v_n; -v_m]; idle last block: F_tau
__global__ __launch_bounds__(TPB) void k_fmv(const int* __restrict__ rptrGn, const int2* __restrict__ pGn,
                                             const int* __restrict__ rptrAr, const int2* __restrict__ pAr,
                                             const float* __restrict__ q, const float* __restrict__ b,
                                             const double* __restrict__ p, const double* __restrict__ pum,
                                             double* __restrict__ Fpc, double* sc, double* red, int it) {
    const int4* pGn4 = (const int4*)pGn;
    const int4* pAr4 = (const int4*)pAr;
    double* ds = red + (long)it * 5 * 64;
    long t = (long)blockIdx.x * TPB + threadIdx.x;
    long i = t >> 1;
    int half = (int)(t & 1);
    int slot = blockIdx.x & 63;
    double ut = p[NMSUM];
    double l1 = 0.0, l2 = 0.0;
    if (i < N_DIM) {
        int ii = (int)i;
        double s = row_dotx4_half(pGn4, rptrGn[ii] >> 1, rptrGn[ii + 1] >> 1, pum, half);
        if (half == 0) {
            double r1 = s + (double)q[ii] * ut;
            double v = (r1 - p[i]) + p[i];
            Fpc[i] = v;
            l1 = (double)q[ii] * v;
        }
    } else if (i < NMSUM) {
        int j = (int)(i - N_DIM);
        double s = row_dotx4_half(pAr4, rptrAr[j] >> 1, rptrAr[j + 1] >> 1, pum, half);
        if (half == 0) {
            double r2 = -s + (double)b[j] * ut;
            double v = (r2 - pum[i]) + p[i];
            Fpc[i] = -v;
            l2 = (double)b[j] * v;
        }
    }
    blk_red_add(l1, ds + 2 * 64 + slot);   // e1
    blk_red_add(l2, ds + 3 * 64 + slot);   // e2
    if (blockIdx.x == gridDim.x - 1) {     // idle block
        double d1 = blk_sum64w(ds + 0 * 64);
        double d2 = blk_sum64w(ds + 1 * 64);
        if (threadIdx.x == 0) {
            double r3 = -d1 - d2 + sc[0] * ut;
            sc[16 + it] = (r3 - ut) + ut;   // F_tau
        }
    }
}

// K3: FTmv — 2-thread-per-row int4 dots over Fpc; Ap + pq; idle last block: tau row
__global__ __launch_bounds__(TPB) void k_ftmv(const int* __restrict__ rptrGn, const int2* __restrict__ pGn,
                                              const int* __restrict__ rptrAr, const int2* __restrict__ pAr,
                                              const float* __restrict__ b, const double* __restrict__ mask_d,
                                              const double* __restrict__ c3,
                                              const double* __restrict__ Fpc, const double* __restrict__ p,
                                              double* __restrict__ Ap, double* sc, double* red, int it) {
    const int4* pGn4 = (const int4*)pGn;
    const int4* pAr4 = (const int4*)pAr;
    double* ds = red + (long)it * 5 * 64;
    long t = (long)blockIdx.x * TPB + threadIdx.x;
    long i = t >> 1;
    int half = (int)(t & 1);
    int slot = blockIdx.x & 63;
    double wt = sc[16 + it];
    double l = 0.0;
    if (i < N_DIM) {
        int ii = (int)i;
        double s = row_dotx4_half(pGn4, rptrGn[ii] >> 1, rptrGn[ii + 1] >> 1, Fpc, half);
        if (half == 0) {
            double v = s - c3[ii] * wt;
            Ap[i] = v;
            l = p[i] * v;
        }
    } else if (i < NMSUM) {
        int j = (int)(i - N_DIM);
        double s = row_dotx4_half(pAr4, rptrAr[j] >> 1, rptrAr[j + 1] >> 1, Fpc, half);
        if (half == 0) {
            double tmv = s - (double)b[j] * wt;
            double wm = -Fpc[i];
            double v = mask_d[j] * (tmv - wm) + wm;
            Ap[i] = v;
            l = p[i] * v;
        }
    }
    blk_red_add(l, ds + 4 * 64 + slot);    // pq (row part)
    if (blockIdx.x == gridDim.x - 1) {
        double e1 = blk_sum64w(ds + 2 * 64);
        double e2 = blk_sum64w(ds + 3 * 64);
        if (threadIdx.x == 0) {
            double tt = e1 + e2 + sc[0] * wt;
            Ap[NMSUM] = tt;
            atomicAdd(ds + 4 * 64 + slot, p[NMSUM] * tt);   // tau term of pq
        }
    }
}

// K4: alpha from slots, x/r update + gam[it+1] slots
__global__ __launch_bounds__(TPB) void k_upd(const double* p, const double* Ap,
                                             double* xcg, double* r, double* red, int it) {
    double* ds = red + (long)it * 5 * 64;
    double* gslot = red + GOFF;
    double gcur = blk_sum64w(gslot + (long)it * 64);
    double pq = blk_sum64w(ds + 4 * 64);
    double alpha = gcur / pq;
    long i = (long)blockIdx.x * TPB + threadIdx.x;
    int slot = blockIdx.x & 63;
    double l = 0.0;
    if (i < NM1) {
        xcg[i] += alpha * p[i];
        double rn = r[i] - alpha * Ap[i];
        r[i] = rn;
        l = rn * rn;
    }
    blk_red_add(l, gslot + (long)(it + 1) * 64 + slot);
}

__global__ __launch_bounds__(TPB) void k_final(const double* xcg, const double* mask_d,
                                               const float* x, const float* y, const float* s,
                                               float* out) {
    int i = blockIdx.x * TPB + threadIdx.x;
    double dzt = xcg[NMSUM];
    if (i < N_DIM) {
        out[i] = (float)(xcg[i] - (double)x[i] * dzt);
    } else if (i < NMSUM) {
        int j = i - N_DIM;
        double dzm = xcg[N_DIM + j];
        double t = mask_d[j] * dzm;
        out[N_DIM + j] = (float)(t - (double)y[j] * dzt);
        out[N_DIM + M_DIM + j] = (float)(t - dzm - (double)s[j] * dzt);
    }
}

extern "C" void kernel_launch(void* const* d_in, const int* in_sizes, int n_in,
                              void* d_out, int out_size, void* d_ws, size_t ws_size,
                              hipStream_t stream) {
    const int*   Pr  = (const int*)d_in[0];
    const int*   Pc  = (const int*)d_in[1];
    const float* Pv  = (const float*)d_in[2];
    const int*   Ar  = (const int*)d_in[3];
    const int*   Ac  = (const int*)d_in[4];
    const float* Av  = (const float*)d_in[5];
    const float* q   = (const float*)d_in[6];
    const float* b   = (const float*)d_in[7];
    const float* x   = (const float*)d_in[8];
    const float* yv  = (const float*)d_in[9];
    const float* sv  = (const float*)d_in[10];
    const float* dPv = (const float*)d_in[11];
    const float* dAv = (const float*)d_in[12];
    const float* dq  = (const float*)d_in[13];
    const float* db  = (const float*)d_in[14];
    float* out = (float*)d_out;

    char* wp = (char*)d_ws;
    auto alloc = [&](size_t bytes) { char* r0 = wp; wp += (bytes + 255) & ~255ull; return r0; };

    double* sc     = (double*)alloc(NSLOT * 8);
    double* red    = (double*)alloc((size_t)REDSZ * 8);
    double* mask_d = (double*)alloc((size_t)M_DIM * 8);
    double* xpim   = (double*)alloc((size_t)NMSUM * 8);   // [x ; pi_m]
    double* c3     = (double*)alloc((size_t)N_DIM * 8);
    double* dd     = (double*)alloc((size_t)NM1 * 8);
    double* r      = (double*)alloc((size_t)NM1 * 8);
    double* p      = (double*)alloc((size_t)NM1 * 8);
    double* xcg    = (double*)alloc((size_t)NM1 * 8);
    double* Ap     = (double*)alloc((size_t)NM1 * 8);
    double* pum    = (double*)alloc((size_t)NMSUM * 8);   // [p_n ; um]
    double* Fpc    = (double*)alloc((size_t)NMSUM * 8);   // [Fp_n ; -Fp_m]
    double* WC     = (double*)alloc((size_t)NMSUM * 8);   // [W_n ; -W_m]
    int2*  pGn    = (int2*)alloc(((size_t)NNZ_GN + N_DIM) * 8);
    int2*  pAr    = (int2*)alloc(((size_t)NNZ_A + M_DIM) * 8);
    float* dvalGn = (float*)alloc(((size_t)NNZ_GN + N_DIM) * 4);
    float* dvalAr = (float*)alloc(((size_t)NNZ_A + M_DIM) * 4);
    int*   rptrGn = (int*)alloc((size_t)(N_DIM + 1) * 4);
    int*   rptrAr = (int*)alloc((size_t)(M_DIM + 1) * 4);
    int*   nP     = (int*)alloc((size_t)N_DIM * 4);
    int*   cntGn  = (int*)alloc((size_t)N_DIM * 4);   // becomes cursor after scan
    int*   cntAr  = (int*)alloc((size_t)M_DIM * 4);   // becomes cursor after scan
    int*   blks   = (int*)alloc(1024 * 4);

    auto g = [](long n) { return dim3((unsigned)((n + TPB - 1) / TPB)); };
    dim3 gs((unsigned)((2L * NM1 + TPB - 1) / TPB + 1));   // split-row grids, +1 idle block

    // ---- CSR build (rows padded to even length) ----
    hipLaunchKernelGGL(k_init, g(NM1), dim3(TPB), 0, stream, sc, yv, sv, x, mask_d, xpim, xcg, red,
                       nP, cntGn, cntAr);
    hipLaunchKernelGGL(k_hist, g(NNZ_A), dim3(TPB), 0, stream, Ar, Ac, Pr, nP, cntGn, cntAr);
    hipLaunchKernelGGL(k_comb, g(M_DIM), dim3(TPB), 0, stream, nP, cntGn, cntAr);

    auto scan = [&](int* cnt, int len, int* rptr) {
        int nb = (len + TPB - 1) / TPB;
        hipLaunchKernelGGL(k_scan1, dim3((unsigned)nb), dim3(TPB), 0, stream, cnt, len, rptr, blks);
        hipLaunchKernelGGL(k_scan2, dim3(1), dim3(1024), 0, stream, blks, nb, rptr + len);
        hipLaunchKernelGGL(k_scan3, dim3((unsigned)nb), dim3(TPB), 0, stream, rptr, blks, len, cnt);
    };
    scan(cntGn, N_DIM, rptrGn);   // cntGn becomes cursor
    scan(cntAr, M_DIM, rptrAr);   // cntAr becomes cursor

    hipLaunchKernelGGL(k_fillGnP, g(NNZ_P), dim3(TPB), 0, stream, Pr, Pc, Pv, dPv, cntGn, pGn, dvalGn);
    hipLaunchKernelGGL(k_fillGnA, g(NNZ_A), dim3(TPB), 0, stream, Ar, Ac, Av, dAv, cntGn, pGn, dvalGn);
    hipLaunchKernelGGL(k_fillAr,  g(NNZ_A), dim3(TPB), 0, stream, Ar, Ac, Av, dAv, cntAr, pAr, dvalAr);
    hipLaunchKernelGGL(k_pad, g(M_DIM), dim3(TPB), 0, stream, cntGn, rptrGn, pGn, dvalGn,
                       cntAr, rptrAr, pAr, dvalAr);

    // ---- setup math (fused) ----
    hipLaunchKernelGGL(k_setup_n, g(N_DIM), dim3(TPB), 0, stream, rptrGn, pGn, dvalGn, nP,
                       xpim, q, dq, c3, dd, red);
    hipLaunchKernelGGL(k_setup_m, g(M_DIM), dim3(TPB), 0, stream, rptrAr, pAr, dvalAr, xpim, db, dd, red);
    hipLaunchKernelGGL(k_negWC, g(NM1), dim3(TPB), 0, stream, dd, WC, q, b, red, sc);
    hipLaunchKernelGGL(k_r, g(NM1), dim3(TPB), 0, stream, rptrGn, pGn, rptrAr, pAr,
                       WC, c3, mask_d, b, dd, r, p, red, sc);

    // ---- 20 CG iterations, 4 fused launches each ----
    for (int it = 0; it < CG_ITERS; ++it) {
        hipLaunchKernelGGL(k_iterA, g(NM1), dim3(TPB), 0, stream, r, p, mask_d, c3, b, pum, red, it);
        hipLaunchKernelGGL(k_fmv,   gs, dim3(TPB), 0, stream, rptrGn, pGn, rptrAr, pAr,
                           q, b, p, pum, Fpc, sc, red, it);
        hipLaunchKernelGGL(k_ftmv,  gs, dim3(TPB), 0, stream, rptrGn, pGn, rptrAr, pAr,
                           b, mask_d, c3, Fpc, p, Ap, sc, red, it);
        hipLaunchKernelGGL(k_upd,   g(NM1), dim3(TPB), 0, stream, p, Ap, xcg, r, red, it);
    }

    hipLaunchKernelGGL(k_final, g(NMSUM), dim3(TPB), 0, stream, xcg, mask_d, x, yv, sv, out);
}

// Round 10
// 2124.392 us; speedup vs baseline: 5.6556x; 1.1029x over previous
//
#include <hip/hip_runtime.h>

#define N_DIM 100000
#define M_DIM 200000
#define NNZ_A 2000000
#define NNZ_P 500000
#define NNZ_GN (NNZ_A + NNZ_P)
#define NMSUM 300000
#define NM1   300001
#define CG_ITERS 20
#define TPB 256
#define NSLOT 512
#define GOFF (20 * 5 * 64)            // gamma slots at red+GOFF, [21][64]
#define SETOFF (GOFF + 21 * 64)       // setup slots: xtpx,s1,s2,s3,s8,s9 each [64]
#define REDSZ (SETOFF + 6 * 64)

// sc[0]=xTPx, sc[16+it]=F_tau, sc[64+it]=gamma_it (published scalar)

__device__ __forceinline__ void blk_red_add(double v, double* dst) {
    __shared__ double sb[TPB];
    int tid = threadIdx.x;
    __syncthreads();
    sb[tid] = v;
    __syncthreads();
    for (int sh = TPB / 2; sh > 0; sh >>= 1) {
        if (tid < sh) sb[tid] += sb[tid + sh];
        __syncthreads();
    }
    if (tid == 0) atomicAdd(dst, sb[0]);
}

// fused pair reduction: one LDS tree pass for two values
__device__ __forceinline__ void blk_red_add2(double v1, double v2, double* d1, double* d2) {
    __shared__ double sb1[TPB];
    __shared__ double sb2[TPB];
    int tid = threadIdx.x;
    __syncthreads();
    sb1[tid] = v1; sb2[tid] = v2;
    __syncthreads();
    for (int sh = TPB / 2; sh > 0; sh >>= 1) {
        if (tid < sh) { sb1[tid] += sb1[tid + sh]; sb2[tid] += sb2[tid + sh]; }
        __syncthreads();
    }
    if (tid == 0) { atomicAdd(d1, sb1[0]); atomicAdd(d2, sb2[0]); }
}

// sum 64 slots, broadcast to all threads of the block
__device__ __forceinline__ double blk_sum64w(const double* src) {
    __shared__ double bsh;
    int t = threadIdx.x;
    if (t < 64) {
        double v = src[t];
        v += __shfl_xor(v, 32); v += __shfl_xor(v, 16); v += __shfl_xor(v, 8);
        v += __shfl_xor(v, 4);  v += __shfl_xor(v, 2);  v += __shfl_xor(v, 1);
        if (t == 0) bsh = v;
    }
    __syncthreads();
    double r = bsh;
    __syncthreads();
    return r;
}

// full-row 2-pair int4 dot (rows padded even; pad = {0,0.0f} -> +0.0)
__device__ __forceinline__ double row_dotx4(const int4* __restrict__ pp, int b2, int e2,
                                            const double* __restrict__ vin) {
    double s = 0.0;
    int k = b2;
    for (; k + 4 <= e2; k += 4) {
        int4 a = pp[k], b = pp[k + 1], c = pp[k + 2], d = pp[k + 3];
        double g0 = vin[a.x], g1 = vin[a.z], g2 = vin[b.x], g3 = vin[b.z];
        double g4 = vin[c.x], g5 = vin[c.z], g6 = vin[d.x], g7 = vin[d.z];
        s += (double)__int_as_float(a.y) * g0;
        s += (double)__int_as_float(a.w) * g1;
        s += (double)__int_as_float(b.y) * g2;
        s += (double)__int_as_float(b.w) * g3;
        s += (double)__int_as_float(c.y) * g4;
        s += (double)__int_as_float(c.w) * g5;
        s += (double)__int_as_float(d.y) * g6;
        s += (double)__int_as_float(d.w) * g7;
    }
    for (; k < e2; ++k) {
        int4 a = pp[k];
        s += (double)__int_as_float(a.y) * vin[a.x];
        s += (double)__int_as_float(a.w) * vin[a.z];
    }
    return s;
}

// 2-thread-per-row: contiguous halves of the int4 slots, one shfl to combine.
__device__ __forceinline__ double row_dotx4_half(const int4* __restrict__ pp, int b2, int e2,
                                                 const double* __restrict__ vin, int half) {
    int len = e2 - b2;
    int h1 = (len + 1) >> 1;
    int kb = b2 + (half ? h1 : 0);
    int ke = half ? e2 : (b2 + h1);
    double s = 0.0;
    int k = kb;
    for (; k + 4 <= ke; k += 4) {
        int4 a = pp[k], b = pp[k + 1], c = pp[k + 2], d = pp[k + 3];
        double g0 = vin[a.x], g1 = vin[a.z], g2 = vin[b.x], g3 = vin[b.z];
        double g4 = vin[c.x], g5 = vin[c.z], g6 = vin[d.x], g7 = vin[d.z];
        s += (double)__int_as_float(a.y) * g0;
        s += (double)__int_as_float(a.w) * g1;
        s += (double)__int_as_float(b.y) * g2;
        s += (double)__int_as_float(b.w) * g3;
        s += (double)__int_as_float(c.y) * g4;
        s += (double)__int_as_float(c.w) * g5;
        s += (double)__int_as_float(d.y) * g6;
        s += (double)__int_as_float(d.w) * g7;
    }
    for (; k + 2 <= ke; k += 2) {
        int4 a = pp[k], b = pp[k + 1];
        double g0 = vin[a.x], g1 = vin[a.z], g2 = vin[b.x], g3 = vin[b.z];
        s += (double)__int_as_float(a.y) * g0;
        s += (double)__int_as_float(a.w) * g1;
        s += (double)__int_as_float(b.y) * g2;
        s += (double)__int_as_float(b.w) * g3;
    }
    if (k < ke) {
        int4 a = pp[k];
        s += (double)__int_as_float(a.y) * vin[a.x];
        s += (double)__int_as_float(a.w) * vin[a.z];
    }
    s += __shfl_xor(s, 1);
    return s;
}

__device__ __forceinline__ double row_dot_d(const int2* __restrict__ pair,
                                            const float* __restrict__ dval, int beg, int end,
                                            const double* __restrict__ vin) {
    double s = 0.0;
    int k = beg;
    for (; k + 4 <= end; k += 4) {
        int c0 = pair[k].x, c1 = pair[k + 1].x, c2 = pair[k + 2].x, c3v = pair[k + 3].x;
        float d0 = dval[k], d1 = dval[k + 1], d2 = dval[k + 2], d3 = dval[k + 3];
        double g0 = vin[c0], g1 = vin[c1], g2 = vin[c2], g3 = vin[c3v];
        s += (double)d0 * g0;
        s += (double)d1 * g1;
        s += (double)d2 * g2;
        s += (double)d3 * g3;
    }
    for (; k < end; ++k)
        s += (double)dval[k] * vin[pair[k].x];
    return s;
}

// ---------------- setup ----------------
__global__ __launch_bounds__(TPB) void k_init(double* sc, const float* y, const float* s,
                                              const float* x, double* mask_d, double* xpim,
                                              double* xcg, double* red,
                                              int* nP, int* cntGn, int* cntAr) {
    long i = (long)blockIdx.x * TPB + threadIdx.x;
    if (i < NSLOT) sc[i] = 0.0;
    if (i < REDSZ) red[i] = 0.0;
    if (i < M_DIM) {
        double v = (double)y[i] - (double)s[i];
        mask_d[i] = v > 0.0 ? 1.0 : 0.0;
        xpim[N_DIM + i] = v > 0.0 ? v : 0.0;   // pi_m
        cntAr[i] = 0;
    }
    if (i < N_DIM) {
        xpim[i] = (double)x[i];
        nP[i] = 0; cntGn[i] = 0;
    }
    if (i < NM1) xcg[i] = 0.0;
}

// histogram; atomic return value = within-row sequence number (stored, reused by fills)
__global__ __launch_bounds__(TPB) void k_hist(const int* Ar, const int* Ac, const int* Pr,
                                              int* nP, int* cntGn, int* cntAr,
                                              int* seqP, int* seqGn, int* seqAr) {
    long k = (long)blockIdx.x * TPB + threadIdx.x;
    if (k < NNZ_A) {
        seqGn[k] = atomicAdd(&cntGn[Ac[k]], 1);
        seqAr[k] = atomicAdd(&cntAr[Ar[k]], 1);
    }
    if (k < NNZ_P) seqP[k] = atomicAdd(&nP[Pr[k]], 1);
}

// cntGn := raw total Gn row length (P + A^T)
__global__ __launch_bounds__(TPB) void k_comb(const int* nP, int* cntGn) {
    int i = blockIdx.x * TPB + threadIdx.x;
    if (i < N_DIM) cntGn[i] += nP[i];
}

// scan with inline even-padding: v = c + (c&1); cnt arrays preserved (raw)
__global__ __launch_bounds__(TPB) void k_scan1(const int* cnt, int len, int* exc, int* blksum) {
    __shared__ int sb[TPB];
    int i = blockIdx.x * TPB + threadIdx.x;
    int c = (i < len) ? cnt[i] : 0;
    int v = c + (c & 1);
    sb[threadIdx.x] = v;
    __syncthreads();
    for (int sh = 1; sh < TPB; sh <<= 1) {
        int t = (threadIdx.x >= sh) ? sb[threadIdx.x - sh] : 0;
        __syncthreads();
        sb[threadIdx.x] += t;
        __syncthreads();
    }
    if (i < len) exc[i] = sb[threadIdx.x] - v;
    if (threadIdx.x == TPB - 1) blksum[blockIdx.x] = sb[TPB - 1];
}

__global__ __launch_bounds__(1024) void k_scan2(int* blksum, int nb, int* total_out) {
    __shared__ int sb[1024];
    int t = threadIdx.x;
    int v = (t < nb) ? blksum[t] : 0;
    sb[t] = v;
    __syncthreads();
    for (int sh = 1; sh < 1024; sh <<= 1) {
        int x = (t >= sh) ? sb[t - sh] : 0;
        __syncthreads();
        sb[t] += x;
        __syncthreads();
    }
    if (t < nb) blksum[t] = sb[t] - v;
    if (t == nb - 1) *total_out = sb[t];
}

__global__ __launch_bounds__(TPB) void k_scan3(int* exc, const int* blksum, int len) {
    int i = blockIdx.x * TPB + threadIdx.x;
    if (i < len) exc[i] += blksum[blockIdx.x];
}

// atomic-FREE fill of G_n (P part + A^T part in one pass; same destination arrays)
__global__ __launch_bounds__(TPB) void k_fillGn(const int* Pr, const int* Pc, const float* Pv,
                                                const float* dPv,
                                                const int* Ar, const int* Ac, const float* Av,
                                                const float* dAv,
                                                const int* rptrGn, const int* nP,
                                                const int* seqP, const int* seqGn,
                                                int2* pGn, float* dvalGn) {
    long k = (long)blockIdx.x * TPB + threadIdx.x;
    if (k < NNZ_P) {
        int r0 = Pr[k];
        int pos = rptrGn[r0] + seqP[k];
        pGn[pos] = make_int2(Pc[k], __float_as_int(Pv[k]));
        dvalGn[pos] = dPv[k];
    }
    if (k < NNZ_A) {
        int c0 = Ac[k];
        int pos = rptrGn[c0] + nP[c0] + seqGn[k];
        pGn[pos] = make_int2(N_DIM + Ar[k], __float_as_int(Av[k]));
        dvalGn[pos] = dAv[k];
    }
}
// atomic-FREE fill of A-by-row
__global__ __launch_bounds__(TPB) void k_fillAr(const int* Ar, const int* Ac, const float* Av,
                                                const float* dAv, const int* rptrAr,
                                                const int* seqAr, int2* pAr, float* dvalAr) {
    long k = (long)blockIdx.x * TPB + threadIdx.x;
    if (k < NNZ_A) {
        int pos = rptrAr[Ar[k]] + seqAr[k];
        pAr[pos] = make_int2(Ac[k], __float_as_int(Av[k]));
        dvalAr[pos] = dAv[k];
    }
}

// zero the (at most one) pad slot per row; raw lens live in cntGn (post-comb) / cntAr
__global__ __launch_bounds__(TPB) void k_pad(const int* cntGn, const int* rptrGn,
                                             int2* pGn, float* dvalGn,
                                             const int* cntAr, const int* rptrAr,
                                             int2* pAr, float* dvalAr) {
    int i = blockIdx.x * TPB + threadIdx.x;
    if (i < N_DIM) {
        int c = cntGn[i];
        if (c & 1) { int pos = rptrGn[i] + c; pGn[pos] = make_int2(0, 0); dvalGn[pos] = 0.0f; }
    }
    if (i < M_DIM) {
        int c = cntAr[i];
        if (c & 1) { int pos = rptrAr[i] + c; pAr[pos] = make_int2(0, 0); dvalAr[pos] = 0.0f; }
    }
}

// fused: c3, dd_n + slot-dots {xtpx, dq.x, x.dpx}
__global__ __launch_bounds__(TPB) void k_setup_n(const int* __restrict__ rptrGn,
                                                 const int2* __restrict__ pGn,
                                                 const float* __restrict__ dvalGn,
                                                 const int* __restrict__ nP,
                                                 const double* __restrict__ xpim,
                                                 const float* __restrict__ q,
                                                 const float* __restrict__ dq,
                                                 double* c3, double* dd, double* red) {
    int i = blockIdx.x * TPB + threadIdx.x;
    int slot = blockIdx.x & 63;
    double* S = red + SETOFF;
    double lx = 0.0, l1 = 0.0, l3 = 0.0;
    if (i < N_DIM) {
        int beg = rptrGn[i], end = rptrGn[i + 1];
        int np = nP[i];
        double px = 0.0, dpxv = 0.0, sa = 0.0;
        for (int k = beg; k < end; ++k) {
            int2 e = pGn[k];
            float dv = dvalGn[k];
            double g = xpim[e.x];
            if (k - beg < np) {
                px += (double)__int_as_float(e.y) * g;
                dpxv += (double)dv * g;
            } else {
                sa += (double)dv * g;
            }
        }
        c3[i] = (double)q[i] + 2.0 * px;
        dd[i] = dpxv + sa + (double)dq[i];
        double xi = xpim[i];
        lx = xi * px;
        l1 = (double)dq[i] * xi;
        l3 = xi * dpxv;
    }
    blk_red_add2(lx, l1, S + 0 * 64 + slot, S + 1 * 64 + slot);   // xTPx, dq.x
    blk_red_add(l3, S + 3 * 64 + slot);                            // x.dpx
}

// fused: dd_m = -(dA x) + db + slot-dot {db.pim}
__global__ __launch_bounds__(TPB) void k_setup_m(const int* __restrict__ rptrAr,
                                                 const int2* __restrict__ pAr,
                                                 const float* __restrict__ dvalAr,
                                                 const double* __restrict__ xpim,
                                                 const float* __restrict__ db, double* dd,
                                                 double* red) {
    int j = blockIdx.x * TPB + threadIdx.x;
    int slot = blockIdx.x & 63;
    double* S = red + SETOFF;
    double l2 = 0.0;
    if (j < M_DIM) {
        double s = row_dot_d(pAr, dvalAr, rptrAr[j], rptrAr[j + 1], xpim);
        dd[N_DIM + j] = -s + (double)db[j];
        l2 = (double)db[j] * xpim[N_DIM + j];
    }
    blk_red_add(l2, S + 2 * 64 + slot);   // db.pim
}

// dd = -dd ; WC = [W_n ; -W_m]; tau thread computes dd[NMSUM] & sc[0]; slot-dots {q.W_n, b.W_m}
__global__ __launch_bounds__(TPB) void k_negWC(double* dd, double* WC,
                                               const float* q, const float* b,
                                               double* red, double* sc) {
    long i = (long)blockIdx.x * TPB + threadIdx.x;
    int slot = blockIdx.x & 63;
    double* S = red + SETOFF;
    double l8 = 0.0, l9 = 0.0;
    if (i == NMSUM) {
        double xt = 0.0, s1 = 0.0, s2 = 0.0, s3 = 0.0;
        for (int k = 0; k < 64; ++k) {
            xt += S[k]; s1 += S[64 + k]; s2 += S[128 + k]; s3 += S[192 + k];
        }
        sc[0] = xt;
        dd[NMSUM] = s1 + s2 + s3;
    } else if (i < NM1) {
        double nv = -dd[i];
        dd[i] = nv;
        if (i < N_DIM) {
            WC[i] = nv;
            l8 = (double)q[i] * nv;
        } else {
            WC[i] = -nv;
            l9 = (double)b[i - N_DIM] * nv;
        }
    }
    blk_red_add2(l8, l9, S + 4 * 64 + slot, S + 5 * 64 + slot);
}

// merged r_n, r_m, r_tau + cginit (p=r, gamma0 slots)
__global__ __launch_bounds__(TPB) void k_r(const int* __restrict__ rptrGn, const int2* __restrict__ pGn,
                                           const int* __restrict__ rptrAr, const int2* __restrict__ pAr,
                                           const double* __restrict__ WC, const double* __restrict__ c3,
                                           const double* __restrict__ mask_d, const float* __restrict__ b,
                                           const double* __restrict__ dd, double* r, double* p,
                                           double* red, const double* sc) {
    const int4* pGn4 = (const int4*)pGn;
    const int4* pAr4 = (const int4*)pAr;
    long i = (long)blockIdx.x * TPB + threadIdx.x;
    int slot = blockIdx.x & 63;
    double* S = red + SETOFF;
    double* gslot = red + GOFF;
    double rv = 0.0;
    bool wr = false;
    if (i < N_DIM) {
        double s = row_dotx4(pGn4, rptrGn[i] >> 1, rptrGn[i + 1] >> 1, WC);
        rv = s - c3[i] * dd[NMSUM];
        wr = true;
    } else if (i < NMSUM) {
        int j = (int)(i - N_DIM);
        double s = row_dotx4(pAr4, rptrAr[j] >> 1, rptrAr[j + 1] >> 1, WC);
        double wt = dd[NMSUM];
        double tmv = s - (double)b[j] * wt;
        double wm = dd[i];
        rv = mask_d[j] * (tmv - wm) + wm;
        wr = true;
    } else if (i == NMSUM) {
        double e1 = 0.0, e2 = 0.0;
        for (int k = 0; k < 64; ++k) { e1 += S[4 * 64 + k]; e2 += S[5 * 64 + k]; }
        rv = e1 + e2 + sc[0] * dd[NMSUM];
        wr = true;
    }
    double l = 0.0;
    if (wr) { r[i] = rv; p[i] = rv; l = rv * rv; }
    blk_red_add(l, gslot + slot);
}

// ---------------- per-iteration kernels (4 launches/iter) ----------------
// K1: p-update + pum + d1,d2; one gamma sum64 (published by block 0 to sc[64+it])
__global__ __launch_bounds__(TPB) void k_iterA(const double* r, double* p,
                                               const double* mask_d, const double* c3,
                                               const float* b, double* pum,
                                               double* red, double* sc, int it) {
    double* ds = red + (long)it * 5 * 64;
    double* gslot = red + GOFF;
    double gn = blk_sum64w(gslot + (long)it * 64);
    if (blockIdx.x == 0 && threadIdx.x == 0) sc[64 + it] = gn;
    double beta = 0.0;
    if (it > 0) beta = gn / sc[64 + it - 1];
    long i = (long)blockIdx.x * TPB + threadIdx.x;
    int slot = blockIdx.x & 63;
    double l1 = 0.0, l2 = 0.0;
    if (i < NM1) {
        double pn;
        if (it > 0) {
            pn = r[i] + beta * p[i];
            p[i] = pn;
        } else {
            pn = p[i];
        }
        if (i < N_DIM) {
            l1 = c3[i] * pn;
            pum[i] = pn;
        } else if (i < NMSUM) {
            int j = (int)(i - N_DIM);
            double u = mask_d[j] * pn;
            pum[i] = u;
            l2 = (double)b[j] * u;
        }
    }
    blk_red_add2(l1, l2, ds + 0 * 64 + slot, ds + 1 * 64 + slot);
}

// K2: Fmv — 2-thread-per-row int4 dots; Fpc=[v_n; -v_m]; idle last block: F_tau
__global__ __launch_bounds__(TPB) void k_fmv(const int* __restrict__ rptrGn, const int2* __restrict__ pGn,
                                             const int* __restrict__ rptrAr, const int2* __restrict__ pAr,
                                             const float* __restrict__ q, const float* __restrict__ b,
                                             const double* __restrict__ p, const double* __restrict__ pum,
                                             double* __restrict__ Fpc, double* sc, double* red, int it) {
    const int4* pGn4 = (const int4*)pGn;
    const int4* pAr4 = (const int4*)pAr;
    double* ds = red + (long)it * 5 * 64;
    long t = (long)blockIdx.x * TPB + threadIdx.x;
    long i = t >> 1;
    int half = (int)(t & 1);
    int slot = blockIdx.x & 63;
    double ut = p[NMSUM];
    double l1 = 0.0, l2 = 0.0;
    if (i < N_DIM) {
        int ii = (int)i;
        double s = row_dotx4_half(pGn4, rptrGn[ii] >> 1, rptrGn[ii + 1] >> 1, pum, half);
        if (half == 0) {
            double r1 = s + (double)q[ii] * ut;
            double v = (r1 - p[i]) + p[i];
            Fpc[i] = v;
            l1 = (double)q[ii] * v;
        }
    } else if (i < NMSUM) {
        int j = (int)(i - N_DIM);
        double s = row_dotx4_half(pAr4, rptrAr[j] >> 1, rptrAr[j + 1] >> 1, pum, half);
        if (half == 0) {
            double r2 = -s + (double)b[j] * ut;
            double v = (r2 - pum[i]) + p[i];
            Fpc[i] = -v;
            l2 = (double)b[j] * v;
        }
    }
    blk_red_add2(l1, l2, ds + 2 * 64 + slot, ds + 3 * 64 + slot);
    if (blockIdx.x == gridDim.x - 1) {
        double d1 = blk_sum64w(ds + 0 * 64);
        double d2 = blk_sum64w(ds + 1 * 64);
        if (threadIdx.x == 0) {
            double r3 = -d1 - d2 + sc[0] * ut;
            sc[16 + it] = (r3 - ut) + ut;   // F_tau
        }
    }
}

// K3: FTmv — 2-thread-per-row int4 dots; Ap + pq; idle last block: tau row
__global__ __launch_bounds__(TPB) void k_ftmv(const int* __restrict__ rptrGn, const int2* __restrict__ pGn,
                                              const int* __restrict__ rptrAr, const int2* __restrict__ pAr,
                                              const float* __restrict__ b, const double* __restrict__ mask_d,
                                              const double* __restrict__ c3,
                                              const double* __restrict__ Fpc, const double* __restrict__ p,
                                              double* __restrict__ Ap, double* sc, double* red, int it) {
    const int4* pGn4 = (const int4*)pGn;
    const int4* pAr4 = (const int4*)pAr;
    double* ds = red + (long)it * 5 * 64;
    long t = (long)blockIdx.x * TPB + threadIdx.x;
    long i = t >> 1;
    int half = (int)(t & 1);
    int slot = blockIdx.x & 63;
    double wt = sc[16 + it];
    double l = 0.0;
    if (i < N_DIM) {
        int ii = (int)i;
        double s = row_dotx4_half(pGn4, rptrGn[ii] >> 1, rptrGn[ii + 1] >> 1, Fpc, half);
        if (half == 0) {
            double v = s - c3[ii] * wt;
            Ap[i] = v;
            l = p[i] * v;
        }
    } else if (i < NMSUM) {
        int j = (int)(i - N_DIM);
        double s = row_dotx4_half(pAr4, rptrAr[j] >> 1, rptrAr[j + 1] >> 1, Fpc, half);
        if (half == 0) {
            double tmv = s - (double)b[j] * wt;
            double wm = -Fpc[i];
            double v = mask_d[j] * (tmv - wm) + wm;
            Ap[i] = v;
            l = p[i] * v;
        }
    }
    blk_red_add(l, ds + 4 * 64 + slot);
    if (blockIdx.x == gridDim.x - 1) {
        double e1 = blk_sum64w(ds + 2 * 64);
        double e2 = blk_sum64w(ds + 3 * 64);
        if (threadIdx.x == 0) {
            double tt = e1 + e2 + sc[0] * wt;
            Ap[NMSUM] = tt;
            atomicAdd(ds + 4 * 64 + slot, p[NMSUM] * tt);
        }
    }
}

// K4: alpha (gamma scalar from sc), x/r update + gam[it+1] slots
__global__ __launch_bounds__(TPB) void k_upd(const double* p, const double* Ap,
                                             double* xcg, double* r, double* red,
                                             const double* sc, int it) {
    double* ds = red + (long)it * 5 * 64;
    double* gslot = red + GOFF;
    double gcur = sc[64 + it];
    double pq = blk_sum64w(ds + 4 * 64);
    double alpha = gcur / pq;
    long i = (long)blockIdx.x * TPB + threadIdx.x;
    int slot = blockIdx.x & 63;
    double l = 0.0;
    if (i < NM1) {
        xcg[i] += alpha * p[i];
        double rn = r[i] - alpha * Ap[i];
        r[i] = rn;
        l = rn * rn;
    }
    blk_red_add(l, gslot + (long)(it + 1) * 64 + slot);
}

__global__ __launch_bounds__(TPB) void k_final(const double* xcg, const double* mask_d,
                                               const float* x, const float* y, const float* s,
                                               float* out) {
    int i = blockIdx.x * TPB + threadIdx.x;
    double dzt = xcg[NMSUM];
    if (i < N_DIM) {
        out[i] = (float)(xcg[i] - (double)x[i] * dzt);
    } else if (i < NMSUM) {
        int j = i - N_DIM;
        double dzm = xcg[N_DIM + j];
        double t = mask_d[j] * dzm;
        out[N_DIM + j] = (float)(t - (double)y[j] * dzt);
        out[N_DIM + M_DIM + j] = (float)(t - dzm - (double)s[j] * dzt);
    }
}

extern "C" void kernel_launch(void* const* d_in, const int* in_sizes, int n_in,
                              void* d_out, int out_size, void* d_ws, size_t ws_size,
                              hipStream_t stream) {
    const int*   Pr  = (const int*)d_in[0];
    const int*   Pc  = (const int*)d_in[1];
    const float* Pv  = (const float*)d_in[2];
    const int*   Ar  = (const int*)d_in[3];
    const int*   Ac  = (const int*)d_in[4];
    const float* Av  = (const float*)d_in[5];
    const float* q   = (const float*)d_in[6];
    const float* b   = (const float*)d_in[7];
    const float* x   = (const float*)d_in[8];
    const float* yv  = (const float*)d_in[9];
    const float* sv  = (const float*)d_in[10];
    const float* dPv = (const float*)d_in[11];
    const float* dAv = (const float*)d_in[12];
    const float* dq  = (const float*)d_in[13];
    const float* db  = (const float*)d_in[14];
    float* out = (float*)d_out;

    char* wp = (char*)d_ws;
    auto alloc = [&](size_t bytes) { char* r0 = wp; wp += (bytes + 255) & ~255ull; return r0; };

    double* sc     = (double*)alloc(NSLOT * 8);
    double* red    = (double*)alloc((size_t)REDSZ * 8);
    double* mask_d = (double*)alloc((size_t)M_DIM * 8);
    double* xpim   = (double*)alloc((size_t)NMSUM * 8);   // [x ; pi_m]
    double* c3     = (double*)alloc((size_t)N_DIM * 8);
    double* dd     = (double*)alloc((size_t)NM1 * 8);
    double* r      = (double*)alloc((size_t)NM1 * 8);
    double* p      = (double*)alloc((size_t)NM1 * 8);
    double* xcg    = (double*)alloc((size_t)NM1 * 8);
    double* Ap     = (double*)alloc((size_t)NM1 * 8);
    double* pum    = (double*)alloc((size_t)NMSUM * 8);   // [p_n ; um]
    double* Fpc    = (double*)alloc((size_t)NMSUM * 8);   // [Fp_n ; -Fp_m]
    double* WC     = (double*)alloc((size_t)NMSUM * 8);   // [W_n ; -W_m]
    int2*  pGn    = (int2*)alloc(((size_t)NNZ_GN + N_DIM) * 8);
    int2*  pAr    = (int2*)alloc(((size_t)NNZ_A + M_DIM) * 8);
    float* dvalGn = (float*)alloc(((size_t)NNZ_GN + N_DIM) * 4);
    float* dvalAr = (float*)alloc(((size_t)NNZ_A + M_DIM) * 4);
    int*   rptrGn = (int*)alloc((size_t)(N_DIM + 1) * 4);
    int*   rptrAr = (int*)alloc((size_t)(M_DIM + 1) * 4);
    int*   nP     = (int*)alloc((size_t)N_DIM * 4);
    int*   cntGn  = (int*)alloc((size_t)N_DIM * 4);
    int*   cntAr  = (int*)alloc((size_t)M_DIM * 4);
    int*   seqP   = (int*)alloc((size_t)NNZ_P * 4);
    int*   seqGn  = (int*)alloc((size_t)NNZ_A * 4);
    int*   seqAr  = (int*)alloc((size_t)NNZ_A * 4);
    int*   blks   = (int*)alloc(1024 * 4);

    auto g = [](long n) { return dim3((unsigned)((n + TPB - 1) / TPB)); };
    dim3 gs((unsigned)((2L * NM1 + TPB - 1) / TPB + 1));   // split-row grids, +1 idle block

    // ---- CSR build ----
    hipLaunchKernelGGL(k_init, g(NM1), dim3(TPB), 0, stream, sc, yv, sv, x, mask_d, xpim, xcg, red,
                       nP, cntGn, cntAr);
    hipLaunchKernelGGL(k_hist, g(NNZ_A), dim3(TPB), 0, stream, Ar, Ac, Pr, nP, cntGn, cntAr,
                       seqP, seqGn, seqAr);
    hipLaunchKernelGGL(k_comb, g(N_DIM), dim3(TPB), 0, stream, nP, cntGn);

    auto scan = [&](int* cnt, int len, int* rptr) {
        int nb = (len + TPB - 1) / TPB;
        hipLaunchKernelGGL(k_scan1, dim3((unsigned)nb), dim3(TPB), 0, stream, cnt, len, rptr, blks);
        hipLaunchKernelGGL(k_scan2, dim3(1), dim3(1024), 0, stream, blks, nb, rptr + len);
        hipLaunchKernelGGL(k_scan3, dim3((unsigned)nb), dim3(TPB), 0, stream, rptr, blks, len);
    };
    scan(cntGn, N_DIM, rptrGn);
    scan(cntAr, M_DIM, rptrAr);

    hipLaunchKernelGGL(k_fillGn, g(NNZ_A), dim3(TPB), 0, stream, Pr, Pc, Pv, dPv,
                       Ar, Ac, Av, dAv, rptrGn, nP, seqP, seqGn, pGn, dvalGn);
    hipLaunchKernelGGL(k_fillAr, g(NNZ_A), dim3(TPB), 0, stream, Ar, Ac, Av, dAv,
                       rptrAr, seqAr, pAr, dvalAr);
    hipLaunchKernelGGL(k_pad, g(M_DIM), dim3(TPB), 0, stream, cntGn, rptrGn, pGn, dvalGn,
                       cntAr, rptrAr, pAr, dvalAr);

    // ---- setup math (fused) ----
    hipLaunchKernelGGL(k_setup_n, g(N_DIM), dim3(TPB), 0, stream, rptrGn, pGn, dvalGn, nP,
                       xpim, q, dq, c3, dd, red);
    hipLaunchKernelGGL(k_setup_m, g(M_DIM), dim3(TPB), 0, stream, rptrAr, pAr, dvalAr, xpim, db, dd, red);
    hipLaunchKernelGGL(k_negWC, g(NM1), dim3(TPB), 0, stream, dd, WC, q, b, red, sc);
    hipLaunchKernelGGL(k_r, g(NM1), dim3(TPB), 0, stream, rptrGn, pGn, rptrAr, pAr,
                       WC, c3, mask_d, b, dd, r, p, red, sc);

    // ---- 20 CG iterations, 4 launches each ----
    for (int it = 0; it < CG_ITERS; ++it) {
        hipLaunchKernelGGL(k_iterA, g(NM1), dim3(TPB), 0, stream, r, p, mask_d, c3, b, pum, red, sc, it);
        hipLaunchKernelGGL(k_fmv,   gs, dim3(TPB), 0, stream, rptrGn, pGn, rptrAr, pAr,
                           q, b, p, pum, Fpc, sc, red, it);
        hipLaunchKernelGGL(k_ftmv,  gs, dim3(TPB), 0, stream, rptrGn, pGn, rptrAr, pAr,
                           b, mask_d, c3, Fpc, p, Ap, sc, red, it);
        hipLaunchKernelGGL(k_upd,   g(NM1), dim3(TPB), 0, stream, p, Ap, xcg, r, red, sc, it);
    }

    hipLaunchKernelGGL(k_final, g(NMSUM), dim3(TPB), 0, stream, xcg, mask_d, x, yv, sv, out);
}